// Round 3
// baseline (387.276 us; speedup 1.0000x reference)
//
#include <hip/hip_runtime.h>
#include <hip/hip_bf16.h>
#include <stdint.h>

typedef _Float16 fp16_t;
typedef __attribute__((ext_vector_type(8))) _Float16 fp16x8;
typedef __attribute__((ext_vector_type(4))) _Float16 fp16x4;
typedef __attribute__((ext_vector_type(4))) float f32x4;

#define WIN 512
#define NG 64

__device__ __forceinline__ void gload16(const void* g, void* l) {
    __builtin_amdgcn_global_load_lds((const __attribute__((address_space(1))) void*)g,
                                     (__attribute__((address_space(3))) void*)l, 16, 0, 0);
}

// ---------------- transpose fp32 [R][C] -> fp16 [C][R] ----------------
__global__ void transpose_f2b(const float* __restrict__ in, fp16_t* __restrict__ out,
                              int R, int C) {
    __shared__ float t[32][33];
    int tx = threadIdx.x, ty = threadIdx.y;
    int c0 = blockIdx.x * 32, r0 = blockIdx.y * 32;
#pragma unroll
    for (int j = 0; j < 32; j += 8)
        t[ty + j][tx] = in[(size_t)(r0 + ty + j) * C + c0 + tx];
    __syncthreads();
#pragma unroll
    for (int j = 0; j < 32; j += 8)
        out[(size_t)(c0 + ty + j) * R + r0 + tx] = (fp16_t)t[tx][ty + j];
}

// ---------------- transpose fp16 slice [R][C] (ld,off) -> fp16 [C][R] ----------------
__global__ void transpose_b2b(const fp16_t* __restrict__ in, fp16_t* __restrict__ out,
                              int R, int C, int in_ld, int in_off) {
    __shared__ fp16_t t[32][33];
    int tx = threadIdx.x, ty = threadIdx.y;
    int c0 = blockIdx.x * 32, r0 = blockIdx.y * 32;
#pragma unroll
    for (int j = 0; j < 32; j += 8)
        t[ty + j][tx] = in[(size_t)(r0 + ty + j) * in_ld + in_off + c0 + tx];
    __syncthreads();
#pragma unroll
    for (int j = 0; j < 32; j += 8)
        out[(size_t)(c0 + ty + j) * R + r0 + tx] = t[tx][ty + j];
}

// ---------------- RMSNorm: fp32 [2048][2048] -> fp16 ----------------
__global__ __launch_bounds__(256) void rmsnorm_kernel(const float* __restrict__ in,
                                                      const float* __restrict__ g,
                                                      fp16_t* __restrict__ out) {
    int row = blockIdx.x;
    int tid = threadIdx.x;
    const float4* rp = (const float4*)(in + (size_t)row * 2048);
    float4 v0 = rp[tid], v1 = rp[tid + 256];
    float ss = v0.x * v0.x + v0.y * v0.y + v0.z * v0.z + v0.w * v0.w +
               v1.x * v1.x + v1.y * v1.y + v1.z * v1.z + v1.w * v1.w;
#pragma unroll
    for (int m = 1; m < 64; m <<= 1) ss += __shfl_xor(ss, m);
    __shared__ float red[4];
    if ((tid & 63) == 0) red[tid >> 6] = ss;
    __syncthreads();
    ss = red[0] + red[1] + red[2] + red[3];
    float sc = rsqrtf(ss * (1.0f / 2048.0f) + 1e-6f);
    const float4* gp = (const float4*)g;
    float4 g0 = gp[tid], g1 = gp[tid + 256];
    fp16x4 o0 = { (fp16_t)(v0.x * sc * g0.x), (fp16_t)(v0.y * sc * g0.y),
                  (fp16_t)(v0.z * sc * g0.z), (fp16_t)(v0.w * sc * g0.w) };
    fp16x4 o1 = { (fp16_t)(v1.x * sc * g1.x), (fp16_t)(v1.y * sc * g1.y),
                  (fp16_t)(v1.z * sc * g1.z), (fp16_t)(v1.w * sc * g1.w) };
    *(fp16x4*)(out + (size_t)row * 2048 + tid * 4) = o0;
    *(fp16x4*)(out + (size_t)row * 2048 + 1024 + tid * 4) = o1;
}

// ---------------- QK-norm in-place on qkv [2048][3072]; q heads also * HD^-0.5 ----------------
__global__ __launch_bounds__(256) void qknorm_kernel(fp16_t* __restrict__ qkv) {
    int seg = blockIdx.x * 4 + (threadIdx.x >> 6);
    int lane = threadIdx.x & 63;
    int row = seg / 20, hs = seg % 20;
    int col0 = hs < 16 ? hs * 128 : 2048 + (hs - 16) * 128;
    fp16_t* p = qkv + (size_t)row * 3072 + col0 + lane * 2;
    float a = (float)p[0], b = (float)p[1];
    float ss = a * a + b * b;
#pragma unroll
    for (int m = 1; m < 64; m <<= 1) ss += __shfl_xor(ss, m);
    float sc = rsqrtf(ss * (1.0f / 128.0f) + 1e-6f);
    if (hs < 16) sc *= 0.08838834764831843f;  // 1/sqrt(128)
    p[0] = (fp16_t)(a * sc);
    p[1] = (fp16_t)(b * sc);
}

// ---------------- silu(u1)*u3 -> u1, n = 2048*5632 ----------------
__global__ __launch_bounds__(256) void silu_mul_kernel(fp16_t* __restrict__ u1,
                                                       const fp16_t* __restrict__ u3) {
    size_t idx = ((size_t)blockIdx.x * 256 + threadIdx.x) * 8;
    fp16x8 a = *(const fp16x8*)(u1 + idx);
    fp16x8 b = *(const fp16x8*)(u3 + idx);
    fp16x8 r;
#pragma unroll
    for (int e = 0; e < 8; ++e) {
        float xg = (float)a[e], xu = (float)b[e];
        float s = xg / (1.0f + __expf(-xg));
        r[e] = (fp16_t)(s * xu);
    }
    *(fp16x8*)(u1 + idx) = r;
}

// ---------------- GEMM: A[M][K] fp16 x Bt[N][K] fp16 -> C[M][N] ----------------
// EPI 0: fp16 out.  EPI 1: fp32 out = acc + resid.
#define BM 128
#define BN 128
#define BKK 64

template <int EPI>
__global__ __launch_bounds__(256, 2) void gemm_bt(const fp16_t* __restrict__ A,
                                                  const fp16_t* __restrict__ Bt,
                                                  void* __restrict__ Cout,
                                                  const float* __restrict__ resid,
                                                  int M, int N, int K) {
    __shared__ __align__(16) char smem[BM * BKK * 2 + BN * BKK * 2];  // 16KB + 16KB
    char* As = smem;
    char* Bs = smem + BM * BKK * 2;

    int tid = threadIdx.x;
    int lane = tid & 63, wid = tid >> 6;
    int lo = lane & 15, hi = lane >> 4;
    int brow = blockIdx.y * BM, bcol = blockIdx.x * BN;
    int wr = (wid >> 1) * 64, wc = (wid & 1) * 64;

    f32x4 acc[4][4] = {};

    int nK = K / BKK;
    for (int kt = 0; kt < nK; ++kt) {
        __syncthreads();
        const char* Abase = (const char*)(A + (size_t)brow * K + kt * BKK);
        const char* Bbase = (const char*)(Bt + (size_t)bcol * K + kt * BKK);
#pragma unroll
        for (int p = 0; p < 4; ++p) {
            int ci = wid * 4 + p;
            int idx = ci * 64 + lane;       // 0..1023
            int row = idx >> 3;             // 0..127
            int cb = (idx & 7) << 4;        // 0..112
            int scb = cb ^ ((row & 7) << 4);
            gload16(Abase + (size_t)row * K * 2 + scb, As + ci * 1024);
            gload16(Bbase + (size_t)row * K * 2 + scb, Bs + ci * 1024);
        }
        __syncthreads();
#pragma unroll
        for (int kc = 0; kc < 2; ++kc) {
            fp16x8 af[4], bfr[4];
            int boff = kc * 64 + hi * 16;
#pragma unroll
            for (int m = 0; m < 4; ++m) {
                int row = wr + m * 16 + lo;
                af[m] = *(const fp16x8*)(As + row * 128 + (boff ^ ((row & 7) << 4)));
            }
#pragma unroll
            for (int n = 0; n < 4; ++n) {
                int row = wc + n * 16 + lo;
                bfr[n] = *(const fp16x8*)(Bs + row * 128 + (boff ^ ((row & 7) << 4)));
            }
#pragma unroll
            for (int m = 0; m < 4; ++m)
#pragma unroll
                for (int n = 0; n < 4; ++n)
                    acc[m][n] = __builtin_amdgcn_mfma_f32_16x16x32_f16(af[m], bfr[n], acc[m][n], 0, 0, 0);
        }
    }

#pragma unroll
    for (int m = 0; m < 4; ++m) {
        int grow0 = brow + wr + m * 16 + hi * 4;
#pragma unroll
        for (int n = 0; n < 4; ++n) {
            int gcol = bcol + wc + n * 16 + lo;
#pragma unroll
            for (int r = 0; r < 4; ++r) {
                size_t gidx = (size_t)(grow0 + r) * N + gcol;
                float v = acc[m][n][r];
                if (EPI == 0) {
                    ((fp16_t*)Cout)[gidx] = (fp16_t)v;
                } else {
                    ((float*)Cout)[gidx] = v + resid[gidx];
                }
            }
        }
    }
}

// ---------------- Flash attention: sliding-window + global, GQA 4:1 ----------------
// grid (32 q-tiles, 16 heads), 256 threads. qkv [2048][3072] fp16 (q|k|v),
// vT [512][2048] fp16 (row = kv*128+d, col = token). o [2048][2048] fp16.
__global__ __launch_bounds__(256, 2) void attn_kernel(const fp16_t* __restrict__ qkv,
                                                      const fp16_t* __restrict__ vT,
                                                      fp16_t* __restrict__ o) {
    __shared__ __align__(16) char smem[16384 + 16384 + 4 * 2304];
    char* Ks = smem;            // [64 keys][128 d] fp16, 256B rows, XOR swizzled
    char* VTs = smem + 16384;   // [128 d][64 keys] fp16, 128B rows, XOR swizzled
    char* Ps = smem + 32768;    // per-wave [16][72] fp16 (144B rows)

    int t = blockIdx.x, qh = blockIdx.y;
    int kvh = qh >> 2;
    int qs = t * 64;
    int tid = threadIdx.x, lane = tid & 63, wid = tid >> 6;
    int lo = lane & 15, hi = lane >> 4;

    // Q fragments (A-operand rows = lo)
    fp16x8 qf[4];
    {
        const fp16_t* qptr = qkv + (size_t)(qs + wid * 16 + lo) * 3072 + qh * 128 + hi * 8;
#pragma unroll
        for (int kc = 0; kc < 4; ++kc) qf[kc] = *(const fp16x8*)(qptr + kc * 32);
    }

    f32x4 oacc[8] = {};
    float m_r[4], l_r[4];
#pragma unroll
    for (int r = 0; r < 4; ++r) { m_r[r] = -1e30f; l_r[r] = 0.0f; }

    int lot = qs - (WIN - 1);
    int jt_lo = lot <= 0 ? 0 : (lot >> 6);
    int nt = (jt_lo > 0) ? (t - jt_lo + 2) : (t + 1);

    for (int ti = 0; ti < nt; ++ti) {
        int jt = (jt_lo > 0) ? (ti == 0 ? 0 : jt_lo + ti - 1) : ti;
        int js = jt * 64;
        __syncthreads();
        // stage K tile (64 rows x 256B) and vT tile (128 rows x 128B)
#pragma unroll
        for (int p = 0; p < 4; ++p) {
            int ci = wid * 4 + p;
            int idx = ci * 64 + lane;  // 0..1023
            int krow = idx >> 4;                      // 0..63
            int kcb = (idx & 15) << 4;                // 0..240
            int kscb = kcb ^ ((krow & 7) << 4);
            gload16((const char*)qkv + ((size_t)(js + krow) * 3072 + 2048 + kvh * 128) * 2 + kscb,
                    Ks + ci * 1024);
            int vrow = idx >> 3;                      // 0..127
            int vcb = (idx & 7) << 4;                 // 0..112
            int vscb = vcb ^ ((vrow & 7) << 4);
            gload16((const char*)vT + ((size_t)(kvh * 128 + vrow) * 2048 + js) * 2 + vscb,
                    VTs + ci * 1024);
        }
        __syncthreads();

        // S = Q K^T  (D rows = q local hi*4+r, cols = key local lo)
        f32x4 s[4] = {};
#pragma unroll
        for (int kc = 0; kc < 4; ++kc) {
#pragma unroll
            for (int jc = 0; jc < 4; ++jc) {
                int row = jc * 16 + lo;
                fp16x8 kf = *(const fp16x8*)(Ks + row * 256 + ((kc * 64 + hi * 16) ^ ((row & 7) << 4)));
                s[jc] = __builtin_amdgcn_mfma_f32_16x16x32_f16(qf[kc], kf, s[jc], 0, 0, 0);
            }
        }

        // mask + online softmax
        float mt[4] = { -1e30f, -1e30f, -1e30f, -1e30f };
#pragma unroll
        for (int jc = 0; jc < 4; ++jc) {
            int j = js + jc * 16 + lo;
#pragma unroll
            for (int r = 0; r < 4; ++r) {
                int i = qs + wid * 16 + hi * 4 + r;
                bool ok = (j <= i) && (((i - j) < WIN) || (j < NG) || (i < NG));
                float sv = ok ? s[jc][r] : -1e30f;
                s[jc][r] = sv;
                mt[r] = fmaxf(mt[r], sv);
            }
        }
#pragma unroll
        for (int m2 = 1; m2 <= 8; m2 <<= 1)
#pragma unroll
            for (int r = 0; r < 4; ++r) mt[r] = fmaxf(mt[r], __shfl_xor(mt[r], m2));
        float sf[4], psum[4];
#pragma unroll
        for (int r = 0; r < 4; ++r) {
            float mn = fmaxf(m_r[r], mt[r]);
            sf[r] = __expf(m_r[r] - mn);
            m_r[r] = mn;
            psum[r] = 0.0f;
        }
#pragma unroll
        for (int jc = 0; jc < 4; ++jc)
#pragma unroll
            for (int r = 0; r < 4; ++r) {
                float p = __expf(s[jc][r] - m_r[r]);
                s[jc][r] = p;
                psum[r] += p;
            }
#pragma unroll
        for (int m2 = 1; m2 <= 8; m2 <<= 1)
#pragma unroll
            for (int r = 0; r < 4; ++r) psum[r] += __shfl_xor(psum[r], m2);
#pragma unroll
        for (int r = 0; r < 4; ++r) l_r[r] = l_r[r] * sf[r] + psum[r];
#pragma unroll
        for (int nc = 0; nc < 8; ++nc)
#pragma unroll
            for (int r = 0; r < 4; ++r) oacc[nc][r] *= sf[r];

        // P -> LDS (wave-private, HW-ordered RAW within wave)
        char* Pb = Ps + wid * 2304;
#pragma unroll
        for (int jc = 0; jc < 4; ++jc)
#pragma unroll
            for (int r = 0; r < 4; ++r)
                *(fp16_t*)(Pb + (hi * 4 + r) * 144 + (jc * 16 + lo) * 2) = (fp16_t)s[jc][r];
        fp16x8 pa[2];
#pragma unroll
        for (int jc2 = 0; jc2 < 2; ++jc2)
            pa[jc2] = *(const fp16x8*)(Pb + lo * 144 + jc2 * 64 + hi * 16);

        // O += P V
#pragma unroll
        for (int jc2 = 0; jc2 < 2; ++jc2)
#pragma unroll
            for (int nc = 0; nc < 8; ++nc) {
                int row = nc * 16 + lo;
                fp16x8 vf = *(const fp16x8*)(VTs + row * 128 + ((jc2 * 64 + hi * 16) ^ ((row & 7) << 4)));
                oacc[nc] = __builtin_amdgcn_mfma_f32_16x16x32_f16(pa[jc2], vf, oacc[nc], 0, 0, 0);
            }
    }

    // epilogue
#pragma unroll
    for (int r = 0; r < 4; ++r) {
        float inv = 1.0f / l_r[r];
        int orow = qs + wid * 16 + hi * 4 + r;
#pragma unroll
        for (int nc = 0; nc < 8; ++nc)
            o[(size_t)orow * 2048 + qh * 128 + nc * 16 + lo] = (fp16_t)(oacc[nc][r] * inv);
    }
}

// ---------------- host ----------------
extern "C" void kernel_launch(void* const* d_in, const int* in_sizes, int n_in,
                              void* d_out, int out_size, void* d_ws, size_t ws_size,
                              hipStream_t stream) {
    // setup_inputs() dict order: x, g_attn, g_ffn, wq, wk, wv, wo, w1, w3, w2
    // (w3 comes BEFORE w2 in the dict — do not use the reference signature order!)
    const float* x = (const float*)d_in[0];
    const float* g_attn = (const float*)d_in[1];
    const float* g_ffn = (const float*)d_in[2];
    const float* wq = (const float*)d_in[3];
    const float* wk = (const float*)d_in[4];
    const float* wv = (const float*)d_in[5];
    const float* wo = (const float*)d_in[6];
    const float* w1 = (const float*)d_in[7];  // gate proj (D,F)
    const float* w3 = (const float*)d_in[8];  // up proj   (D,F)  <- dict order!
    const float* w2 = (const float*)d_in[9];  // down proj (F,D)  <- dict order!
    float* out = (float*)d_out;

    char* ws = (char*)d_ws;
    size_t off = 0;
    auto alloc = [&](size_t bytes) {
        char* p = ws + off;
        off += (bytes + 255) & ~(size_t)255;
        return p;
    };
    fp16_t* wqkvT = (fp16_t*)alloc(3072ull * 2048 * 2);  // later reused for woT
    fp16_t* wbigT = (fp16_t*)alloc(5632ull * 2048 * 2);  // w1T / w3T / w2T sequentially
    fp16_t* hbuf  = (fp16_t*)alloc(2048ull * 2048 * 2);  // h, then attn out o
    fp16_t* qkv   = (fp16_t*)alloc(2048ull * 3072 * 2);  // qkv, then h2
    fp16_t* vTb   = (fp16_t*)alloc(512ull * 2048 * 2);
    float*  x1    = (float*)alloc(2048ull * 2048 * 4);
    fp16_t* u1    = (fp16_t*)alloc(2048ull * 5632 * 2);
    fp16_t* u3    = (fp16_t*)alloc(2048ull * 5632 * 2);
    if (off > ws_size) {  // diagnostic fallback: absmax ~= max|ref|
        hipMemsetAsync(d_out, 0, (size_t)out_size * 4, stream);
        return;
    }

    dim3 tb(32, 8);
    // QKV weights -> [N][K] fp16 concat
    transpose_f2b<<<dim3(64, 64), tb, 0, stream>>>(wq, wqkvT, 2048, 2048);
    transpose_f2b<<<dim3(16, 64), tb, 0, stream>>>(wk, wqkvT + 2048ull * 2048, 2048, 512);
    transpose_f2b<<<dim3(16, 64), tb, 0, stream>>>(wv, wqkvT + 2560ull * 2048, 2048, 512);
    // h = RMSNorm(x) * g_attn
    rmsnorm_kernel<<<2048, 256, 0, stream>>>(x, g_attn, hbuf);
    // qkv = h @ [wq|wk|wv]
    gemm_bt<0><<<dim3(24, 16), 256, 0, stream>>>(hbuf, wqkvT, qkv, nullptr, 2048, 3072, 2048);
    // qk-norm (+ q * HD^-0.5)
    qknorm_kernel<<<10240, 256, 0, stream>>>(qkv);
    // vT
    transpose_b2b<<<dim3(16, 64), tb, 0, stream>>>(qkv, vTb, 2048, 512, 3072, 2560);
    // attention -> o (reuses hbuf)
    attn_kernel<<<dim3(32, 16), 256, 0, stream>>>(qkv, vTb, hbuf);
    // x1 = x + o @ wo
    transpose_f2b<<<dim3(64, 64), tb, 0, stream>>>(wo, wqkvT, 2048, 2048);
    gemm_bt<1><<<dim3(16, 16), 256, 0, stream>>>(hbuf, wqkvT, x1, x, 2048, 2048, 2048);
    // h2 = RMSNorm(x1) * g_ffn  (reuses qkv buffer)
    rmsnorm_kernel<<<2048, 256, 0, stream>>>(x1, g_ffn, qkv);
    // u1 = h2 @ w1 ; u3 = h2 @ w3
    transpose_f2b<<<dim3(176, 64), tb, 0, stream>>>(w1, wbigT, 2048, 5632);
    gemm_bt<0><<<dim3(44, 16), 256, 0, stream>>>(qkv, wbigT, u1, nullptr, 2048, 5632, 2048);
    transpose_f2b<<<dim3(176, 64), tb, 0, stream>>>(w3, wbigT, 2048, 5632);
    gemm_bt<0><<<dim3(44, 16), 256, 0, stream>>>(qkv, wbigT, u3, nullptr, 2048, 5632, 2048);
    // g = silu(u1) * u3 (in place in u1)
    silu_mul_kernel<<<5632, 256, 0, stream>>>(u1, u3);
    // out = x1 + g @ w2
    transpose_f2b<<<dim3(64, 176), tb, 0, stream>>>(w2, wbigT, 5632, 2048);
    gemm_bt<1><<<dim3(16, 16), 256, 0, stream>>>(u1, wbigT, out, x1, 2048, 2048, 5632);
}

// Round 4
// 350.873 us; speedup vs baseline: 1.1037x; 1.1037x over previous
//
#include <hip/hip_runtime.h>
#include <hip/hip_bf16.h>
#include <stdint.h>

typedef _Float16 fp16_t;
typedef __attribute__((ext_vector_type(8))) _Float16 fp16x8;
typedef __attribute__((ext_vector_type(4))) _Float16 fp16x4;
typedef __attribute__((ext_vector_type(4))) float f32x4;

#define WIN 512
#define NG 64

__device__ __forceinline__ void gload16(const void* g, void* l) {
    __builtin_amdgcn_global_load_lds((const __attribute__((address_space(1))) void*)g,
                                     (__attribute__((address_space(3))) void*)l, 16, 0, 0);
}

// ---------------- transpose fp32 [R][C] -> fp16 [C][R], 64x64 tiles ----------------
__global__ void transpose_f2b(const float* __restrict__ in, fp16_t* __restrict__ out,
                              int R, int C) {
    __shared__ fp16_t t[64][66];  // stride 66 fp16 = 132B = 33 dwords -> conflict-free column read
    int tx = threadIdx.x, ty = threadIdx.y;  // (64, 8)
    int c0 = blockIdx.x * 64, r0 = blockIdx.y * 64;
#pragma unroll
    for (int j = 0; j < 64; j += 8)
        t[ty + j][tx] = (fp16_t)in[(size_t)(r0 + ty + j) * C + c0 + tx];
    __syncthreads();
#pragma unroll
    for (int j = 0; j < 64; j += 8)
        out[(size_t)(c0 + ty + j) * R + r0 + tx] = t[tx][ty + j];
}

// ---------------- transpose fp16 slice [R][C] (ld,off) -> fp16 [C][R] ----------------
__global__ void transpose_b2b(const fp16_t* __restrict__ in, fp16_t* __restrict__ out,
                              int R, int C, int in_ld, int in_off) {
    __shared__ fp16_t t[32][33];
    int tx = threadIdx.x, ty = threadIdx.y;
    int c0 = blockIdx.x * 32, r0 = blockIdx.y * 32;
#pragma unroll
    for (int j = 0; j < 32; j += 8)
        t[ty + j][tx] = in[(size_t)(r0 + ty + j) * in_ld + in_off + c0 + tx];
    __syncthreads();
#pragma unroll
    for (int j = 0; j < 32; j += 8)
        out[(size_t)(c0 + ty + j) * R + r0 + tx] = t[tx][ty + j];
}

// ---------------- RMSNorm: fp32 [2048][2048] -> fp16 ----------------
__global__ __launch_bounds__(256) void rmsnorm_kernel(const float* __restrict__ in,
                                                      const float* __restrict__ g,
                                                      fp16_t* __restrict__ out) {
    int row = blockIdx.x;
    int tid = threadIdx.x;
    const float4* rp = (const float4*)(in + (size_t)row * 2048);
    float4 v0 = rp[tid], v1 = rp[tid + 256];
    float ss = v0.x * v0.x + v0.y * v0.y + v0.z * v0.z + v0.w * v0.w +
               v1.x * v1.x + v1.y * v1.y + v1.z * v1.z + v1.w * v1.w;
#pragma unroll
    for (int m = 1; m < 64; m <<= 1) ss += __shfl_xor(ss, m);
    __shared__ float red[4];
    if ((tid & 63) == 0) red[tid >> 6] = ss;
    __syncthreads();
    ss = red[0] + red[1] + red[2] + red[3];
    float sc = rsqrtf(ss * (1.0f / 2048.0f) + 1e-6f);
    const float4* gp = (const float4*)g;
    float4 g0 = gp[tid], g1 = gp[tid + 256];
    fp16x4 o0 = { (fp16_t)(v0.x * sc * g0.x), (fp16_t)(v0.y * sc * g0.y),
                  (fp16_t)(v0.z * sc * g0.z), (fp16_t)(v0.w * sc * g0.w) };
    fp16x4 o1 = { (fp16_t)(v1.x * sc * g1.x), (fp16_t)(v1.y * sc * g1.y),
                  (fp16_t)(v1.z * sc * g1.z), (fp16_t)(v1.w * sc * g1.w) };
    *(fp16x4*)(out + (size_t)row * 2048 + tid * 4) = o0;
    *(fp16x4*)(out + (size_t)row * 2048 + 1024 + tid * 4) = o1;
}

// ---------------- x1 = x + p0 + p1 (write fp32), h2 = RMSNorm(x1)*g (write fp16) ----------------
__global__ __launch_bounds__(256) void rmsnorm_add2(const float* __restrict__ xin,
                                                    const float* __restrict__ p0,
                                                    const float* __restrict__ p1,
                                                    const float* __restrict__ g,
                                                    float* __restrict__ x1out,
                                                    fp16_t* __restrict__ hout) {
    int row = blockIdx.x;
    int tid = threadIdx.x;
    size_t base = (size_t)row * 2048;
    const float4* xp = (const float4*)(xin + base);
    const float4* ap = (const float4*)(p0 + base);
    const float4* bp = (const float4*)(p1 + base);
    float4 v0 = xp[tid], v1 = xp[tid + 256];
    float4 a0 = ap[tid], a1 = ap[tid + 256];
    float4 b0 = bp[tid], b1 = bp[tid + 256];
    v0.x += a0.x + b0.x; v0.y += a0.y + b0.y; v0.z += a0.z + b0.z; v0.w += a0.w + b0.w;
    v1.x += a1.x + b1.x; v1.y += a1.y + b1.y; v1.z += a1.z + b1.z; v1.w += a1.w + b1.w;
    float ss = v0.x * v0.x + v0.y * v0.y + v0.z * v0.z + v0.w * v0.w +
               v1.x * v1.x + v1.y * v1.y + v1.z * v1.z + v1.w * v1.w;
#pragma unroll
    for (int m = 1; m < 64; m <<= 1) ss += __shfl_xor(ss, m);
    __shared__ float red[4];
    if ((tid & 63) == 0) red[tid >> 6] = ss;
    __syncthreads();
    ss = red[0] + red[1] + red[2] + red[3];
    float sc = rsqrtf(ss * (1.0f / 2048.0f) + 1e-6f);
    ((float4*)(x1out + base))[tid] = v0;
    ((float4*)(x1out + base))[tid + 256] = v1;
    const float4* gp = (const float4*)g;
    float4 g0 = gp[tid], g1 = gp[tid + 256];
    fp16x4 o0 = { (fp16_t)(v0.x * sc * g0.x), (fp16_t)(v0.y * sc * g0.y),
                  (fp16_t)(v0.z * sc * g0.z), (fp16_t)(v0.w * sc * g0.w) };
    fp16x4 o1 = { (fp16_t)(v1.x * sc * g1.x), (fp16_t)(v1.y * sc * g1.y),
                  (fp16_t)(v1.z * sc * g1.z), (fp16_t)(v1.w * sc * g1.w) };
    *(fp16x4*)(hout + base + tid * 4) = o0;
    *(fp16x4*)(hout + base + 1024 + tid * 4) = o1;
}

// ---------------- out += p0 + p1 (fp32, in place on d_out) ----------------
__global__ __launch_bounds__(256) void final_add2(float* __restrict__ out,
                                                  const float* __restrict__ p0,
                                                  const float* __restrict__ p1) {
    size_t i = (size_t)blockIdx.x * 256 + threadIdx.x;
    float4 o = ((const float4*)out)[i];
    float4 a = ((const float4*)p0)[i];
    float4 b = ((const float4*)p1)[i];
    o.x += a.x + b.x; o.y += a.y + b.y; o.z += a.z + b.z; o.w += a.w + b.w;
    ((float4*)out)[i] = o;
}

// ---------------- QK-norm in-place on qkv [2048][3072]; q heads also * HD^-0.5 ----------------
__global__ __launch_bounds__(256) void qknorm_kernel(fp16_t* __restrict__ qkv) {
    int seg = blockIdx.x * 4 + (threadIdx.x >> 6);
    int lane = threadIdx.x & 63;
    int row = seg / 20, hs = seg % 20;
    int col0 = hs < 16 ? hs * 128 : 2048 + (hs - 16) * 128;
    fp16_t* p = qkv + (size_t)row * 3072 + col0 + lane * 2;
    float a = (float)p[0], b = (float)p[1];
    float ss = a * a + b * b;
#pragma unroll
    for (int m = 1; m < 64; m <<= 1) ss += __shfl_xor(ss, m);
    float sc = rsqrtf(ss * (1.0f / 128.0f) + 1e-6f);
    if (hs < 16) sc *= 0.08838834764831843f;  // 1/sqrt(128)
    p[0] = (fp16_t)(a * sc);
    p[1] = (fp16_t)(b * sc);
}

// ---------------- silu(u1)*u3 -> u1, n = 2048*5632 ----------------
__global__ __launch_bounds__(256) void silu_mul_kernel(fp16_t* __restrict__ u1,
                                                       const fp16_t* __restrict__ u3) {
    size_t idx = ((size_t)blockIdx.x * 256 + threadIdx.x) * 8;
    fp16x8 a = *(const fp16x8*)(u1 + idx);
    fp16x8 b = *(const fp16x8*)(u3 + idx);
    fp16x8 r;
#pragma unroll
    for (int e = 0; e < 8; ++e) {
        float xg = (float)a[e], xu = (float)b[e];
        float s = xg / (1.0f + __expf(-xg));
        r[e] = (fp16_t)(s * xu);
    }
    *(fp16x8*)(u1 + idx) = r;
}

// ---------------- GEMM: A[M][K] fp16 x Bt[N][K] fp16 -> C[M][N] ----------------
// Double-buffered 2-phase pipeline: stage(t+1) overlaps compute(t), 1 barrier/K-step.
// EPI 0: fp16 out.  EPI 1: fp32 out = acc + resid.  EPI 2: fp32 partial at z-slice.
#define BM 128
#define BN 128
#define BKK 64

template <int EPI>
__global__ __launch_bounds__(256, 2) void gemm_bt(const fp16_t* __restrict__ A,
                                                  const fp16_t* __restrict__ Bt,
                                                  void* __restrict__ Cout,
                                                  const float* __restrict__ resid,
                                                  int M, int N, int K,
                                                  int lda, int ldb, int ksplit) {
    __shared__ __align__(16) char smem[2][32768];  // [buf][A 16KB | B 16KB]

    int tid = threadIdx.x;
    int lane = tid & 63, wid = tid >> 6;
    int lo = lane & 15, hi = lane >> 4;
    int brow = blockIdx.y * BM, bcol = blockIdx.x * BN;
    int wr = (wid >> 1) * 64, wc = (wid & 1) * 64;

    int Kloc = K / ksplit;
    int kbase0 = blockIdx.z * Kloc;
    int nK = Kloc / BKK;

    // per-thread staging geometry (constant across tiles)
    int arow[4], ascb[4];
#pragma unroll
    for (int p = 0; p < 4; ++p) {
        int idx = (wid * 4 + p) * 64 + lane;
        int row = idx >> 3;
        int cb = (idx & 7) << 4;
        arow[p] = row;
        ascb[p] = cb ^ ((row & 7) << 4);
    }

    f32x4 acc[4][4] = {};

    auto stage = [&](int buf, int kb) {
        char* As = smem[buf];
        char* Bs = smem[buf] + 16384;
#pragma unroll
        for (int p = 0; p < 4; ++p) {
            int ci = wid * 4 + p;
            gload16((const char*)A + ((size_t)(brow + arow[p]) * lda + kb) * 2 + ascb[p],
                    As + ci * 1024);
            gload16((const char*)Bt + ((size_t)(bcol + arow[p]) * ldb + kb) * 2 + ascb[p],
                    Bs + ci * 1024);
        }
    };

    auto compute = [&](int buf) {
        char* As = smem[buf];
        char* Bs = smem[buf] + 16384;
#pragma unroll
        for (int kc = 0; kc < 2; ++kc) {
            fp16x8 af[4], bfr[4];
            int boff = kc * 64 + hi * 16;
#pragma unroll
            for (int m = 0; m < 4; ++m) {
                int row = wr + m * 16 + lo;
                af[m] = *(const fp16x8*)(As + row * 128 + (boff ^ ((row & 7) << 4)));
            }
#pragma unroll
            for (int n = 0; n < 4; ++n) {
                int row = wc + n * 16 + lo;
                bfr[n] = *(const fp16x8*)(Bs + row * 128 + (boff ^ ((row & 7) << 4)));
            }
#pragma unroll
            for (int m = 0; m < 4; ++m)
#pragma unroll
                for (int n = 0; n < 4; ++n)
                    acc[m][n] = __builtin_amdgcn_mfma_f32_16x16x32_f16(af[m], bfr[n], acc[m][n], 0, 0, 0);
        }
    };

    stage(0, kbase0);
    __syncthreads();
    for (int kt = 0; kt < nK; ++kt) {
        if (kt + 1 < nK) stage((kt + 1) & 1, kbase0 + (kt + 1) * BKK);
        compute(kt & 1);
        __syncthreads();
    }

#pragma unroll
    for (int m = 0; m < 4; ++m) {
        int grow0 = brow + wr + m * 16 + hi * 4;
#pragma unroll
        for (int n = 0; n < 4; ++n) {
            int gcol = bcol + wc + n * 16 + lo;
#pragma unroll
            for (int r = 0; r < 4; ++r) {
                size_t gidx = (size_t)(grow0 + r) * N + gcol;
                float v = acc[m][n][r];
                if (EPI == 0) {
                    ((fp16_t*)Cout)[gidx] = (fp16_t)v;
                } else if (EPI == 1) {
                    ((float*)Cout)[gidx] = v + resid[gidx];
                } else {
                    ((float*)Cout)[(size_t)blockIdx.z * M * N + gidx] = v;
                }
            }
        }
    }
}

// ---------------- Flash attention: sliding-window + global, GQA 4:1 ----------------
__global__ __launch_bounds__(256, 2) void attn_kernel(const fp16_t* __restrict__ qkv,
                                                      const fp16_t* __restrict__ vT,
                                                      fp16_t* __restrict__ o) {
    __shared__ __align__(16) char smem[16384 + 16384 + 4 * 2304];
    char* Ks = smem;            // [64 keys][128 d] fp16, 256B rows, XOR swizzled
    char* VTs = smem + 16384;   // [128 d][64 keys] fp16, 128B rows, XOR swizzled
    char* Ps = smem + 32768;    // per-wave [16][72] fp16 (144B rows)

    int t = blockIdx.x, qh = blockIdx.y;
    int kvh = qh >> 2;
    int qs = t * 64;
    int tid = threadIdx.x, lane = tid & 63, wid = tid >> 6;
    int lo = lane & 15, hi = lane >> 4;

    fp16x8 qf[4];
    {
        const fp16_t* qptr = qkv + (size_t)(qs + wid * 16 + lo) * 3072 + qh * 128 + hi * 8;
#pragma unroll
        for (int kc = 0; kc < 4; ++kc) qf[kc] = *(const fp16x8*)(qptr + kc * 32);
    }

    f32x4 oacc[8] = {};
    float m_r[4], l_r[4];
#pragma unroll
    for (int r = 0; r < 4; ++r) { m_r[r] = -1e30f; l_r[r] = 0.0f; }

    int lot = qs - (WIN - 1);
    int jt_lo = lot <= 0 ? 0 : (lot >> 6);
    int nt = (jt_lo > 0) ? (t - jt_lo + 2) : (t + 1);

    for (int ti = 0; ti < nt; ++ti) {
        int jt = (jt_lo > 0) ? (ti == 0 ? 0 : jt_lo + ti - 1) : ti;
        int js = jt * 64;
        __syncthreads();
#pragma unroll
        for (int p = 0; p < 4; ++p) {
            int ci = wid * 4 + p;
            int idx = ci * 64 + lane;
            int krow = idx >> 4;
            int kcb = (idx & 15) << 4;
            int kscb = kcb ^ ((krow & 7) << 4);
            gload16((const char*)qkv + ((size_t)(js + krow) * 3072 + 2048 + kvh * 128) * 2 + kscb,
                    Ks + ci * 1024);
            int vrow = idx >> 3;
            int vcb = (idx & 7) << 4;
            int vscb = vcb ^ ((vrow & 7) << 4);
            gload16((const char*)vT + ((size_t)(kvh * 128 + vrow) * 2048 + js) * 2 + vscb,
                    VTs + ci * 1024);
        }
        __syncthreads();

        f32x4 s[4] = {};
#pragma unroll
        for (int kc = 0; kc < 4; ++kc) {
#pragma unroll
            for (int jc = 0; jc < 4; ++jc) {
                int row = jc * 16 + lo;
                fp16x8 kf = *(const fp16x8*)(Ks + row * 256 + ((kc * 64 + hi * 16) ^ ((row & 7) << 4)));
                s[jc] = __builtin_amdgcn_mfma_f32_16x16x32_f16(qf[kc], kf, s[jc], 0, 0, 0);
            }
        }

        float mt[4] = { -1e30f, -1e30f, -1e30f, -1e30f };
#pragma unroll
        for (int jc = 0; jc < 4; ++jc) {
            int j = js + jc * 16 + lo;
#pragma unroll
            for (int r = 0; r < 4; ++r) {
                int i = qs + wid * 16 + hi * 4 + r;
                bool ok = (j <= i) && (((i - j) < WIN) || (j < NG) || (i < NG));
                float sv = ok ? s[jc][r] : -1e30f;
                s[jc][r] = sv;
                mt[r] = fmaxf(mt[r], sv);
            }
        }
#pragma unroll
        for (int m2 = 1; m2 <= 8; m2 <<= 1)
#pragma unroll
            for (int r = 0; r < 4; ++r) mt[r] = fmaxf(mt[r], __shfl_xor(mt[r], m2));
        float sf[4], psum[4];
#pragma unroll
        for (int r = 0; r < 4; ++r) {
            float mn = fmaxf(m_r[r], mt[r]);
            sf[r] = __expf(m_r[r] - mn);
            m_r[r] = mn;
            psum[r] = 0.0f;
        }
#pragma unroll
        for (int jc = 0; jc < 4; ++jc)
#pragma unroll
            for (int r = 0; r < 4; ++r) {
                float p = __expf(s[jc][r] - m_r[r]);
                s[jc][r] = p;
                psum[r] += p;
            }
#pragma unroll
        for (int m2 = 1; m2 <= 8; m2 <<= 1)
#pragma unroll
            for (int r = 0; r < 4; ++r) psum[r] += __shfl_xor(psum[r], m2);
#pragma unroll
        for (int r = 0; r < 4; ++r) l_r[r] = l_r[r] * sf[r] + psum[r];
#pragma unroll
        for (int nc = 0; nc < 8; ++nc)
#pragma unroll
            for (int r = 0; r < 4; ++r) oacc[nc][r] *= sf[r];

        char* Pb = Ps + wid * 2304;
#pragma unroll
        for (int jc = 0; jc < 4; ++jc)
#pragma unroll
            for (int r = 0; r < 4; ++r)
                *(fp16_t*)(Pb + (hi * 4 + r) * 144 + (jc * 16 + lo) * 2) = (fp16_t)s[jc][r];
        fp16x8 pa[2];
#pragma unroll
        for (int jc2 = 0; jc2 < 2; ++jc2)
            pa[jc2] = *(const fp16x8*)(Pb + lo * 144 + jc2 * 64 + hi * 16);

#pragma unroll
        for (int jc2 = 0; jc2 < 2; ++jc2)
#pragma unroll
            for (int nc = 0; nc < 8; ++nc) {
                int row = nc * 16 + lo;
                fp16x8 vf = *(const fp16x8*)(VTs + row * 128 + ((jc2 * 64 + hi * 16) ^ ((row & 7) << 4)));
                oacc[nc] = __builtin_amdgcn_mfma_f32_16x16x32_f16(pa[jc2], vf, oacc[nc], 0, 0, 0);
            }
    }

#pragma unroll
    for (int r = 0; r < 4; ++r) {
        float inv = 1.0f / l_r[r];
        int orow = qs + wid * 16 + hi * 4 + r;
#pragma unroll
        for (int nc = 0; nc < 8; ++nc)
            o[(size_t)orow * 2048 + qh * 128 + nc * 16 + lo] = (fp16_t)(oacc[nc][r] * inv);
    }
}

// ---------------- host ----------------
extern "C" void kernel_launch(void* const* d_in, const int* in_sizes, int n_in,
                              void* d_out, int out_size, void* d_ws, size_t ws_size,
                              hipStream_t stream) {
    // setup_inputs() dict order: x, g_attn, g_ffn, wq, wk, wv, wo, w1, w3, w2
    const float* x = (const float*)d_in[0];
    const float* g_attn = (const float*)d_in[1];
    const float* g_ffn = (const float*)d_in[2];
    const float* wq = (const float*)d_in[3];
    const float* wk = (const float*)d_in[4];
    const float* wv = (const float*)d_in[5];
    const float* wo = (const float*)d_in[6];
    const float* w1 = (const float*)d_in[7];  // gate proj (D,F)
    const float* w3 = (const float*)d_in[8];  // up proj   (D,F)  <- dict order!
    const float* w2 = (const float*)d_in[9];  // down proj (F,D)  <- dict order!
    float* out = (float*)d_out;               // doubles as x1 buffer

    char* ws = (char*)d_ws;
    size_t off = 0;
    auto alloc = [&](size_t bytes) {
        char* p = ws + off;
        off += (bytes + 255) & ~(size_t)255;
        return p;
    };
    fp16_t* wqkvT = (fp16_t*)alloc(3072ull * 2048 * 2);  // later reused for woT
    fp16_t* wbigT = (fp16_t*)alloc(5632ull * 2048 * 2);  // w1T / w3T / w2T sequentially
    fp16_t* hbuf  = (fp16_t*)alloc(2048ull * 2048 * 2);  // h, then attn out o
    fp16_t* qkv   = (fp16_t*)alloc(2048ull * 3072 * 2);  // qkv, then h2
    fp16_t* vTb   = (fp16_t*)alloc(512ull * 2048 * 2);
    fp16_t* u1    = (fp16_t*)alloc(2048ull * 5632 * 2);
    fp16_t* u3    = (fp16_t*)alloc(2048ull * 5632 * 2);
    float*  part  = (float*)alloc(2ull * 2048 * 2048 * 4);  // split-K partials (wo, then w2)
    if (off > ws_size) {  // diagnostic fallback: absmax ~= max|ref|
        hipMemsetAsync(d_out, 0, (size_t)out_size * 4, stream);
        return;
    }
    float* part1 = part + 2048ull * 2048;

    dim3 tb64(64, 8);
    // QKV weights -> [N][K] fp16 concat
    transpose_f2b<<<dim3(32, 32), tb64, 0, stream>>>(wq, wqkvT, 2048, 2048);
    transpose_f2b<<<dim3(8, 32), tb64, 0, stream>>>(wk, wqkvT + 2048ull * 2048, 2048, 512);
    transpose_f2b<<<dim3(8, 32), tb64, 0, stream>>>(wv, wqkvT + 2560ull * 2048, 2048, 512);
    // h = RMSNorm(x) * g_attn
    rmsnorm_kernel<<<2048, 256, 0, stream>>>(x, g_attn, hbuf);
    // qkv = h @ [wq|wk|wv]
    gemm_bt<0><<<dim3(24, 16, 1), 256, 0, stream>>>(hbuf, wqkvT, qkv, nullptr,
                                                    2048, 3072, 2048, 2048, 2048, 1);
    // qk-norm (+ q * HD^-0.5)
    qknorm_kernel<<<10240, 256, 0, stream>>>(qkv);
    // vT
    transpose_b2b<<<dim3(16, 64), dim3(32, 8), 0, stream>>>(qkv, vTb, 2048, 512, 3072, 2560);
    // attention -> o (reuses hbuf)
    attn_kernel<<<dim3(32, 16), 256, 0, stream>>>(qkv, vTb, hbuf);
    // wo partials (split-K=2): part[z] = o @ wo[z-half]
    transpose_f2b<<<dim3(32, 32), tb64, 0, stream>>>(wo, wqkvT, 2048, 2048);
    gemm_bt<2><<<dim3(16, 16, 2), 256, 0, stream>>>(hbuf, wqkvT, part, nullptr,
                                                    2048, 2048, 2048, 2048, 2048, 2);
    // x1 = x + p0 + p1 (-> d_out); h2 = RMSNorm(x1)*g_ffn (-> qkv buffer)
    rmsnorm_add2<<<2048, 256, 0, stream>>>(x, part, part1, g_ffn, out, qkv);
    // u1 = h2 @ w1 ; u3 = h2 @ w3
    transpose_f2b<<<dim3(88, 32), tb64, 0, stream>>>(w1, wbigT, 2048, 5632);
    gemm_bt<0><<<dim3(44, 16, 1), 256, 0, stream>>>(qkv, wbigT, u1, nullptr,
                                                    2048, 5632, 2048, 2048, 2048, 1);
    transpose_f2b<<<dim3(88, 32), tb64, 0, stream>>>(w3, wbigT, 2048, 5632);
    gemm_bt<0><<<dim3(44, 16, 1), 256, 0, stream>>>(qkv, wbigT, u3, nullptr,
                                                    2048, 5632, 2048, 2048, 2048, 1);
    // g = silu(u1) * u3 (in place in u1)
    silu_mul_kernel<<<5632, 256, 0, stream>>>(u1, u3);
    // down-proj partials (split-K=2): part[z] = g @ w2[z-half]
    transpose_f2b<<<dim3(32, 88), tb64, 0, stream>>>(w2, wbigT, 5632, 2048);
    gemm_bt<2><<<dim3(16, 16, 2), 256, 0, stream>>>(u1, wbigT, part, nullptr,
                                                    2048, 2048, 5632, 5632, 5632, 2);
    // out = x1 + q0 + q1 (in place on d_out)
    final_add2<<<4096, 256, 0, stream>>>(out, part, part1);
}

// Round 5
// 337.760 us; speedup vs baseline: 1.1466x; 1.0388x over previous
//
#include <hip/hip_runtime.h>
#include <hip/hip_bf16.h>
#include <stdint.h>

typedef _Float16 fp16_t;
typedef __attribute__((ext_vector_type(8))) _Float16 fp16x8;
typedef __attribute__((ext_vector_type(4))) _Float16 fp16x4;
typedef __attribute__((ext_vector_type(4))) float f32x4;

#define WIN 512
#define NG 64

__device__ __forceinline__ void gload16(const void* g, void* l) {
    __builtin_amdgcn_global_load_lds((const __attribute__((address_space(1))) void*)g,
                                     (__attribute__((address_space(3))) void*)l, 16, 0, 0);
}

// ---------------- transpose fp32 [R][C] -> fp16 [C][R], 64x64 tiles, vectorized ----------------
// block 256 threads: float4 reads (16B/lane), fp16x4 writes (8B/lane)
__global__ __launch_bounds__(256) void transpose_f2b(const float* __restrict__ in,
                                                     fp16_t* __restrict__ out,
                                                     int R, int C) {
    __shared__ fp16_t t[64][68];  // [c][r], stride 68 keeps fp16x4 reads 8B-aligned
    int tid = threadIdx.x;
    int tx = tid & 15, ty = tid >> 4;
    int c0 = blockIdx.x * 64, r0 = blockIdx.y * 64;
#pragma unroll
    for (int j = 0; j < 4; ++j) {
        int r = ty + j * 16;
        float4 v = *(const float4*)&in[(size_t)(r0 + r) * C + c0 + tx * 4];
        t[tx * 4 + 0][r] = (fp16_t)v.x;
        t[tx * 4 + 1][r] = (fp16_t)v.y;
        t[tx * 4 + 2][r] = (fp16_t)v.z;
        t[tx * 4 + 3][r] = (fp16_t)v.w;
    }
    __syncthreads();
#pragma unroll
    for (int jj = 0; jj < 4; ++jj) {
        int c_l = ty + jj * 16;
        int r_l = tx * 4;
        *(fp16x4*)&out[(size_t)(c0 + c_l) * R + r0 + r_l] = *(const fp16x4*)&t[c_l][r_l];
    }
}

// ---------------- transpose fp16 slice [R][C] (ld,off) -> fp16 [C][R] ----------------
__global__ void transpose_b2b(const fp16_t* __restrict__ in, fp16_t* __restrict__ out,
                              int R, int C, int in_ld, int in_off) {
    __shared__ fp16_t t[32][33];
    int tx = threadIdx.x, ty = threadIdx.y;
    int c0 = blockIdx.x * 32, r0 = blockIdx.y * 32;
#pragma unroll
    for (int j = 0; j < 32; j += 8)
        t[ty + j][tx] = in[(size_t)(r0 + ty + j) * in_ld + in_off + c0 + tx];
    __syncthreads();
#pragma unroll
    for (int j = 0; j < 32; j += 8)
        out[(size_t)(c0 + ty + j) * R + r0 + tx] = t[tx][ty + j];
}

// ---------------- RMSNorm: fp32 [2048][2048] -> fp16 ----------------
__global__ __launch_bounds__(256) void rmsnorm_kernel(const float* __restrict__ in,
                                                      const float* __restrict__ g,
                                                      fp16_t* __restrict__ out) {
    int row = blockIdx.x;
    int tid = threadIdx.x;
    const float4* rp = (const float4*)(in + (size_t)row * 2048);
    float4 v0 = rp[tid], v1 = rp[tid + 256];
    float ss = v0.x * v0.x + v0.y * v0.y + v0.z * v0.z + v0.w * v0.w +
               v1.x * v1.x + v1.y * v1.y + v1.z * v1.z + v1.w * v1.w;
#pragma unroll
    for (int m = 1; m < 64; m <<= 1) ss += __shfl_xor(ss, m);
    __shared__ float red[4];
    if ((tid & 63) == 0) red[tid >> 6] = ss;
    __syncthreads();
    ss = red[0] + red[1] + red[2] + red[3];
    float sc = rsqrtf(ss * (1.0f / 2048.0f) + 1e-6f);
    const float4* gp = (const float4*)g;
    float4 g0 = gp[tid], g1 = gp[tid + 256];
    fp16x4 o0 = { (fp16_t)(v0.x * sc * g0.x), (fp16_t)(v0.y * sc * g0.y),
                  (fp16_t)(v0.z * sc * g0.z), (fp16_t)(v0.w * sc * g0.w) };
    fp16x4 o1 = { (fp16_t)(v1.x * sc * g1.x), (fp16_t)(v1.y * sc * g1.y),
                  (fp16_t)(v1.z * sc * g1.z), (fp16_t)(v1.w * sc * g1.w) };
    *(fp16x4*)(out + (size_t)row * 2048 + tid * 4) = o0;
    *(fp16x4*)(out + (size_t)row * 2048 + 1024 + tid * 4) = o1;
}

// ---------------- x1 = x + p0 + p1 (write fp32), h2 = RMSNorm(x1)*g (write fp16) ----------------
__global__ __launch_bounds__(256) void rmsnorm_add2(const float* __restrict__ xin,
                                                    const float* __restrict__ p0,
                                                    const float* __restrict__ p1,
                                                    const float* __restrict__ g,
                                                    float* __restrict__ x1out,
                                                    fp16_t* __restrict__ hout) {
    int row = blockIdx.x;
    int tid = threadIdx.x;
    size_t base = (size_t)row * 2048;
    const float4* xp = (const float4*)(xin + base);
    const float4* ap = (const float4*)(p0 + base);
    const float4* bp = (const float4*)(p1 + base);
    float4 v0 = xp[tid], v1 = xp[tid + 256];
    float4 a0 = ap[tid], a1 = ap[tid + 256];
    float4 b0 = bp[tid], b1 = bp[tid + 256];
    v0.x += a0.x + b0.x; v0.y += a0.y + b0.y; v0.z += a0.z + b0.z; v0.w += a0.w + b0.w;
    v1.x += a1.x + b1.x; v1.y += a1.y + b1.y; v1.z += a1.z + b1.z; v1.w += a1.w + b1.w;
    float ss = v0.x * v0.x + v0.y * v0.y + v0.z * v0.z + v0.w * v0.w +
               v1.x * v1.x + v1.y * v1.y + v1.z * v1.z + v1.w * v1.w;
#pragma unroll
    for (int m = 1; m < 64; m <<= 1) ss += __shfl_xor(ss, m);
    __shared__ float red[4];
    if ((tid & 63) == 0) red[tid >> 6] = ss;
    __syncthreads();
    ss = red[0] + red[1] + red[2] + red[3];
    float sc = rsqrtf(ss * (1.0f / 2048.0f) + 1e-6f);
    ((float4*)(x1out + base))[tid] = v0;
    ((float4*)(x1out + base))[tid + 256] = v1;
    const float4* gp = (const float4*)g;
    float4 g0 = gp[tid], g1 = gp[tid + 256];
    fp16x4 o0 = { (fp16_t)(v0.x * sc * g0.x), (fp16_t)(v0.y * sc * g0.y),
                  (fp16_t)(v0.z * sc * g0.z), (fp16_t)(v0.w * sc * g0.w) };
    fp16x4 o1 = { (fp16_t)(v1.x * sc * g1.x), (fp16_t)(v1.y * sc * g1.y),
                  (fp16_t)(v1.z * sc * g1.z), (fp16_t)(v1.w * sc * g1.w) };
    *(fp16x4*)(hout + base + tid * 4) = o0;
    *(fp16x4*)(hout + base + 1024 + tid * 4) = o1;
}

// ---------------- out += p0 + p1 (fp32, in place on d_out) ----------------
__global__ __launch_bounds__(256) void final_add2(float* __restrict__ out,
                                                  const float* __restrict__ p0,
                                                  const float* __restrict__ p1) {
    size_t i = (size_t)blockIdx.x * 256 + threadIdx.x;
    float4 o = ((const float4*)out)[i];
    float4 a = ((const float4*)p0)[i];
    float4 b = ((const float4*)p1)[i];
    o.x += a.x + b.x; o.y += a.y + b.y; o.z += a.z + b.z; o.w += a.w + b.w;
    ((float4*)out)[i] = o;
}

// ---------------- QK-norm in-place on qkv [2048][3072]; q heads also * HD^-0.5 ----------------
__global__ __launch_bounds__(256) void qknorm_kernel(fp16_t* __restrict__ qkv) {
    int seg = blockIdx.x * 4 + (threadIdx.x >> 6);
    int lane = threadIdx.x & 63;
    int row = seg / 20, hs = seg % 20;
    int col0 = hs < 16 ? hs * 128 : 2048 + (hs - 16) * 128;
    fp16_t* p = qkv + (size_t)row * 3072 + col0 + lane * 2;
    float a = (float)p[0], b = (float)p[1];
    float ss = a * a + b * b;
#pragma unroll
    for (int m = 1; m < 64; m <<= 1) ss += __shfl_xor(ss, m);
    float sc = rsqrtf(ss * (1.0f / 128.0f) + 1e-6f);
    if (hs < 16) sc *= 0.08838834764831843f;  // 1/sqrt(128)
    p[0] = (fp16_t)(a * sc);
    p[1] = (fp16_t)(b * sc);
}

// ---------------- silu(u1)*u3 -> u1, n = 2048*5632 ----------------
__global__ __launch_bounds__(256) void silu_mul_kernel(fp16_t* __restrict__ u1,
                                                       const fp16_t* __restrict__ u3) {
    size_t idx = ((size_t)blockIdx.x * 256 + threadIdx.x) * 8;
    fp16x8 a = *(const fp16x8*)(u1 + idx);
    fp16x8 b = *(const fp16x8*)(u3 + idx);
    fp16x8 r;
#pragma unroll
    for (int e = 0; e < 8; ++e) {
        float xg = (float)a[e], xu = (float)b[e];
        float s = xg / (1.0f + __expf(-xg));
        r[e] = (fp16_t)(s * xu);
    }
    *(fp16x8*)(u1 + idx) = r;
}

// ---------------- GEMM core (shared body) ----------------
#define BM 128
#define BN 128
#define BKK 64

struct GemmCore {
    int tid, lane, wid, lo, hi, wr, wc;
    int arow[4], ascb[4];
    __device__ __forceinline__ void init(int t) {
        tid = t; lane = t & 63; wid = t >> 6;
        lo = lane & 15; hi = lane >> 4;
        wr = (wid >> 1) * 64; wc = (wid & 1) * 64;
#pragma unroll
        for (int p = 0; p < 4; ++p) {
            int idx = (wid * 4 + p) * 64 + lane;
            int row = idx >> 3;
            int cb = (idx & 7) << 4;
            arow[p] = row;
            ascb[p] = cb ^ ((row & 7) << 4);
        }
    }
    __device__ __forceinline__ void stage(char* buf, const fp16_t* A, const fp16_t* Bt,
                                          int brow, int bcol, int lda, int ldb, int kb) {
        char* As = buf;
        char* Bs = buf + 16384;
#pragma unroll
        for (int p = 0; p < 4; ++p) {
            int ci = wid * 4 + p;
            gload16((const char*)A + ((size_t)(brow + arow[p]) * lda + kb) * 2 + ascb[p],
                    As + ci * 1024);
            gload16((const char*)Bt + ((size_t)(bcol + arow[p]) * ldb + kb) * 2 + ascb[p],
                    Bs + ci * 1024);
        }
    }
    __device__ __forceinline__ void compute(const char* buf, f32x4 (&acc)[4][4]) {
        const char* As = buf;
        const char* Bs = buf + 16384;
#pragma unroll
        for (int kc = 0; kc < 2; ++kc) {
            fp16x8 af[4], bfr[4];
            int boff = kc * 64 + hi * 16;
#pragma unroll
            for (int m = 0; m < 4; ++m) {
                int row = wr + m * 16 + lo;
                af[m] = *(const fp16x8*)(As + row * 128 + (boff ^ ((row & 7) << 4)));
            }
#pragma unroll
            for (int n = 0; n < 4; ++n) {
                int row = wc + n * 16 + lo;
                bfr[n] = *(const fp16x8*)(Bs + row * 128 + (boff ^ ((row & 7) << 4)));
            }
#pragma unroll
            for (int m = 0; m < 4; ++m)
#pragma unroll
                for (int n = 0; n < 4; ++n)
                    acc[m][n] = __builtin_amdgcn_mfma_f32_16x16x32_f16(af[m], bfr[n], acc[m][n], 0, 0, 0);
        }
    }
};

// EPI 0: fp16 out.  EPI 1: fp32 out = acc + resid.  EPI 2: fp32 partial at z-slice.
template <int EPI>
__global__ __launch_bounds__(256, 2) void gemm_bt(const fp16_t* __restrict__ A,
                                                  const fp16_t* __restrict__ Bt,
                                                  void* __restrict__ Cout,
                                                  const float* __restrict__ resid,
                                                  int M, int N, int K,
                                                  int lda, int ldb, int ksplit) {
    __shared__ __align__(16) char smem[2][32768];
    GemmCore g;
    g.init(threadIdx.x);
    int brow = blockIdx.y * BM, bcol = blockIdx.x * BN;

    int Kloc = K / ksplit;
    int kbase0 = blockIdx.z * Kloc;
    int nK = Kloc / BKK;

    f32x4 acc[4][4] = {};
    g.stage(smem[0], A, Bt, brow, bcol, lda, ldb, kbase0);
    __syncthreads();
    for (int kt = 0; kt < nK; ++kt) {
        if (kt + 1 < nK) g.stage(smem[(kt + 1) & 1], A, Bt, brow, bcol, lda, ldb,
                                 kbase0 + (kt + 1) * BKK);
        g.compute(smem[kt & 1], acc);
        __syncthreads();
    }

#pragma unroll
    for (int m = 0; m < 4; ++m) {
        int grow0 = brow + g.wr + m * 16 + g.hi * 4;
#pragma unroll
        for (int n = 0; n < 4; ++n) {
            int gcol = bcol + g.wc + n * 16 + g.lo;
#pragma unroll
            for (int r = 0; r < 4; ++r) {
                size_t gidx = (size_t)(grow0 + r) * N + gcol;
                float v = acc[m][n][r];
                if (EPI == 0) {
                    ((fp16_t*)Cout)[gidx] = (fp16_t)v;
                } else if (EPI == 1) {
                    ((float*)Cout)[gidx] = v + resid[gidx];
                } else {
                    ((float*)Cout)[(size_t)blockIdx.z * M * N + gidx] = v;
                }
            }
        }
    }
}

// Dual GEMM: z selects (Bt0->C0) or (Bt1->C1); shared A. fp16 out.
__global__ __launch_bounds__(256, 2) void gemm_bt_dual(const fp16_t* __restrict__ A,
                                                       const fp16_t* __restrict__ Bt0,
                                                       const fp16_t* __restrict__ Bt1,
                                                       fp16_t* __restrict__ C0,
                                                       fp16_t* __restrict__ C1,
                                                       int M, int N, int K) {
    __shared__ __align__(16) char smem[2][32768];
    GemmCore g;
    g.init(threadIdx.x);
    const fp16_t* Bt = blockIdx.z ? Bt1 : Bt0;
    fp16_t* Cout = blockIdx.z ? C1 : C0;
    int brow = blockIdx.y * BM, bcol = blockIdx.x * BN;
    int nK = K / BKK;

    f32x4 acc[4][4] = {};
    g.stage(smem[0], A, Bt, brow, bcol, K, K, 0);
    __syncthreads();
    for (int kt = 0; kt < nK; ++kt) {
        if (kt + 1 < nK) g.stage(smem[(kt + 1) & 1], A, Bt, brow, bcol, K, K, (kt + 1) * BKK);
        g.compute(smem[kt & 1], acc);
        __syncthreads();
    }

#pragma unroll
    for (int m = 0; m < 4; ++m) {
        int grow0 = brow + g.wr + m * 16 + g.hi * 4;
#pragma unroll
        for (int n = 0; n < 4; ++n) {
            int gcol = bcol + g.wc + n * 16 + g.lo;
#pragma unroll
            for (int r = 0; r < 4; ++r)
                Cout[(size_t)(grow0 + r) * N + gcol] = (fp16_t)acc[m][n][r];
        }
    }
}

// ---------------- Flash attention: sliding-window + global, GQA 4:1 ----------------
__global__ __launch_bounds__(256, 2) void attn_kernel(const fp16_t* __restrict__ qkv,
                                                      const fp16_t* __restrict__ vT,
                                                      fp16_t* __restrict__ o) {
    __shared__ __align__(16) char smem[16384 + 16384 + 4 * 2304];
    char* Ks = smem;
    char* VTs = smem + 16384;
    char* Ps = smem + 32768;

    int t = blockIdx.x, qh = blockIdx.y;
    int kvh = qh >> 2;
    int qs = t * 64;
    int tid = threadIdx.x, lane = tid & 63, wid = tid >> 6;
    int lo = lane & 15, hi = lane >> 4;

    fp16x8 qf[4];
    {
        const fp16_t* qptr = qkv + (size_t)(qs + wid * 16 + lo) * 3072 + qh * 128 + hi * 8;
#pragma unroll
        for (int kc = 0; kc < 4; ++kc) qf[kc] = *(const fp16x8*)(qptr + kc * 32);
    }

    f32x4 oacc[8] = {};
    float m_r[4], l_r[4];
#pragma unroll
    for (int r = 0; r < 4; ++r) { m_r[r] = -1e30f; l_r[r] = 0.0f; }

    int lot = qs - (WIN - 1);
    int jt_lo = lot <= 0 ? 0 : (lot >> 6);
    int nt = (jt_lo > 0) ? (t - jt_lo + 2) : (t + 1);

    for (int ti = 0; ti < nt; ++ti) {
        int jt = (jt_lo > 0) ? (ti == 0 ? 0 : jt_lo + ti - 1) : ti;
        int js = jt * 64;
        __syncthreads();
#pragma unroll
        for (int p = 0; p < 4; ++p) {
            int ci = wid * 4 + p;
            int idx = ci * 64 + lane;
            int krow = idx >> 4;
            int kcb = (idx & 15) << 4;
            int kscb = kcb ^ ((krow & 7) << 4);
            gload16((const char*)qkv + ((size_t)(js + krow) * 3072 + 2048 + kvh * 128) * 2 + kscb,
                    Ks + ci * 1024);
            int vrow = idx >> 3;
            int vcb = (idx & 7) << 4;
            int vscb = vcb ^ ((vrow & 7) << 4);
            gload16((const char*)vT + ((size_t)(kvh * 128 + vrow) * 2048 + js) * 2 + vscb,
                    VTs + ci * 1024);
        }
        __syncthreads();

        f32x4 s[4] = {};
#pragma unroll
        for (int kc = 0; kc < 4; ++kc) {
#pragma unroll
            for (int jc = 0; jc < 4; ++jc) {
                int row = jc * 16 + lo;
                fp16x8 kf = *(const fp16x8*)(Ks + row * 256 + ((kc * 64 + hi * 16) ^ ((row & 7) << 4)));
                s[jc] = __builtin_amdgcn_mfma_f32_16x16x32_f16(qf[kc], kf, s[jc], 0, 0, 0);
            }
        }

        float mt[4] = { -1e30f, -1e30f, -1e30f, -1e30f };
#pragma unroll
        for (int jc = 0; jc < 4; ++jc) {
            int j = js + jc * 16 + lo;
#pragma unroll
            for (int r = 0; r < 4; ++r) {
                int i = qs + wid * 16 + hi * 4 + r;
                bool ok = (j <= i) && (((i - j) < WIN) || (j < NG) || (i < NG));
                float sv = ok ? s[jc][r] : -1e30f;
                s[jc][r] = sv;
                mt[r] = fmaxf(mt[r], sv);
            }
        }
#pragma unroll
        for (int m2 = 1; m2 <= 8; m2 <<= 1)
#pragma unroll
            for (int r = 0; r < 4; ++r) mt[r] = fmaxf(mt[r], __shfl_xor(mt[r], m2));
        float sf[4], psum[4];
#pragma unroll
        for (int r = 0; r < 4; ++r) {
            float mn = fmaxf(m_r[r], mt[r]);
            sf[r] = __expf(m_r[r] - mn);
            m_r[r] = mn;
            psum[r] = 0.0f;
        }
#pragma unroll
        for (int jc = 0; jc < 4; ++jc)
#pragma unroll
            for (int r = 0; r < 4; ++r) {
                float p = __expf(s[jc][r] - m_r[r]);
                s[jc][r] = p;
                psum[r] += p;
            }
#pragma unroll
        for (int m2 = 1; m2 <= 8; m2 <<= 1)
#pragma unroll
            for (int r = 0; r < 4; ++r) psum[r] += __shfl_xor(psum[r], m2);
#pragma unroll
        for (int r = 0; r < 4; ++r) l_r[r] = l_r[r] * sf[r] + psum[r];
#pragma unroll
        for (int nc = 0; nc < 8; ++nc)
#pragma unroll
            for (int r = 0; r < 4; ++r) oacc[nc][r] *= sf[r];

        char* Pb = Ps + wid * 2304;
#pragma unroll
        for (int jc = 0; jc < 4; ++jc)
#pragma unroll
            for (int r = 0; r < 4; ++r)
                *(fp16_t*)(Pb + (hi * 4 + r) * 144 + (jc * 16 + lo) * 2) = (fp16_t)s[jc][r];
        fp16x8 pa[2];
#pragma unroll
        for (int jc2 = 0; jc2 < 2; ++jc2)
            pa[jc2] = *(const fp16x8*)(Pb + lo * 144 + jc2 * 64 + hi * 16);

#pragma unroll
        for (int jc2 = 0; jc2 < 2; ++jc2)
#pragma unroll
            for (int nc = 0; nc < 8; ++nc) {
                int row = nc * 16 + lo;
                fp16x8 vf = *(const fp16x8*)(VTs + row * 128 + ((jc2 * 64 + hi * 16) ^ ((row & 7) << 4)));
                oacc[nc] = __builtin_amdgcn_mfma_f32_16x16x32_f16(pa[jc2], vf, oacc[nc], 0, 0, 0);
            }
    }

#pragma unroll
    for (int r = 0; r < 4; ++r) {
        float inv = 1.0f / l_r[r];
        int orow = qs + wid * 16 + hi * 4 + r;
#pragma unroll
        for (int nc = 0; nc < 8; ++nc)
            o[(size_t)orow * 2048 + qh * 128 + nc * 16 + lo] = (fp16_t)(oacc[nc][r] * inv);
    }
}

// ---------------- host ----------------
extern "C" void kernel_launch(void* const* d_in, const int* in_sizes, int n_in,
                              void* d_out, int out_size, void* d_ws, size_t ws_size,
                              hipStream_t stream) {
    // setup_inputs() dict order: x, g_attn, g_ffn, wq, wk, wv, wo, w1, w3, w2
    const float* x = (const float*)d_in[0];
    const float* g_attn = (const float*)d_in[1];
    const float* g_ffn = (const float*)d_in[2];
    const float* wq = (const float*)d_in[3];
    const float* wk = (const float*)d_in[4];
    const float* wv = (const float*)d_in[5];
    const float* wo = (const float*)d_in[6];
    const float* w1 = (const float*)d_in[7];  // gate proj (D,F)
    const float* w3 = (const float*)d_in[8];  // up proj   (D,F)  <- dict order!
    const float* w2 = (const float*)d_in[9];  // down proj (F,D)  <- dict order!
    float* out = (float*)d_out;               // doubles as x1 buffer

    char* ws = (char*)d_ws;
    size_t off = 0;
    auto alloc = [&](size_t bytes) {
        char* p = ws + off;
        off += (bytes + 255) & ~(size_t)255;
        return p;
    };
    // Order matters: hbuf+wqkvT+vTb are contiguous (8.39+12.58+2.10 = 23.07MB)
    // and all dead by FFN time -> overlaid by w3T (5632*2048*2 = 23.07MB exactly).
    fp16_t* hbuf  = (fp16_t*)alloc(2048ull * 2048 * 2);  // h, then attn out o
    fp16_t* wqkvT = (fp16_t*)alloc(3072ull * 2048 * 2);  // qkv weights, then woT
    fp16_t* vTb   = (fp16_t*)alloc(512ull * 2048 * 2);
    fp16_t* qkv   = (fp16_t*)alloc(2048ull * 3072 * 2);  // qkv, then h2
    fp16_t* u1    = (fp16_t*)alloc(2048ull * 5632 * 2);
    fp16_t* u3    = (fp16_t*)alloc(2048ull * 5632 * 2);
    float*  part  = (float*)alloc(2ull * 2048 * 2048 * 4);  // split-K partials
    fp16_t* wbigT = (fp16_t*)alloc(5632ull * 2048 * 2);  // w1T, then w2T
    if (off > ws_size) {  // diagnostic fallback: absmax ~= max|ref|
        hipMemsetAsync(d_out, 0, (size_t)out_size * 4, stream);
        return;
    }
    float* part1 = part + 2048ull * 2048;
    fp16_t* w3T = hbuf;  // overlay (valid only after wo GEMM)

    // QKV weights -> [N][K] fp16 concat
    transpose_f2b<<<dim3(32, 32), 256, 0, stream>>>(wq, wqkvT, 2048, 2048);
    transpose_f2b<<<dim3(8, 32), 256, 0, stream>>>(wk, wqkvT + 2048ull * 2048, 2048, 512);
    transpose_f2b<<<dim3(8, 32), 256, 0, stream>>>(wv, wqkvT + 2560ull * 2048, 2048, 512);
    // h = RMSNorm(x) * g_attn
    rmsnorm_kernel<<<2048, 256, 0, stream>>>(x, g_attn, hbuf);
    // qkv = h @ [wq|wk|wv]
    gemm_bt<0><<<dim3(24, 16, 1), 256, 0, stream>>>(hbuf, wqkvT, qkv, nullptr,
                                                    2048, 3072, 2048, 2048, 2048, 1);
    // qk-norm (+ q * HD^-0.5)
    qknorm_kernel<<<10240, 256, 0, stream>>>(qkv);
    // vT
    transpose_b2b<<<dim3(16, 64), dim3(32, 8), 0, stream>>>(qkv, vTb, 2048, 512, 3072, 2560);
    // attention -> o (reuses hbuf; h no longer needed)
    attn_kernel<<<dim3(32, 16), 256, 0, stream>>>(qkv, vTb, hbuf);
    // wo partials (split-K=2)
    transpose_f2b<<<dim3(32, 32), 256, 0, stream>>>(wo, wqkvT, 2048, 2048);
    gemm_bt<2><<<dim3(16, 16, 2), 256, 0, stream>>>(hbuf, wqkvT, part, nullptr,
                                                    2048, 2048, 2048, 2048, 2048, 2);
    // x1 = x + p0 + p1 (-> d_out); h2 = RMSNorm(x1)*g_ffn (-> qkv buffer)
    rmsnorm_add2<<<2048, 256, 0, stream>>>(x, part, part1, g_ffn, out, qkv);
    // u1 = h2 @ w1 ; u3 = h2 @ w3 (dual dispatch; w3T overlays dead hbuf/wqkvT/vTb)
    transpose_f2b<<<dim3(88, 32), 256, 0, stream>>>(w1, wbigT, 2048, 5632);
    transpose_f2b<<<dim3(88, 32), 256, 0, stream>>>(w3, w3T, 2048, 5632);
    gemm_bt_dual<<<dim3(44, 16, 2), 256, 0, stream>>>(qkv, wbigT, w3T, u1, u3,
                                                      2048, 5632, 2048);
    // g = silu(u1) * u3 (in place in u1)
    silu_mul_kernel<<<5632, 256, 0, stream>>>(u1, u3);
    // down-proj partials (split-K=2)
    transpose_f2b<<<dim3(32, 88), 256, 0, stream>>>(w2, wbigT, 5632, 2048);
    gemm_bt<2><<<dim3(16, 16, 2), 256, 0, stream>>>(u1, wbigT, part, nullptr,
                                                    2048, 2048, 5632, 5632, 5632, 2);
    // out = x1 + q0 + q1 (in place on d_out)
    final_add2<<<4096, 256, 0, stream>>>(out, part, part1);
}

// Round 6
// 323.507 us; speedup vs baseline: 1.1971x; 1.0441x over previous
//
#include <hip/hip_runtime.h>
#include <hip/hip_bf16.h>
#include <stdint.h>

typedef _Float16 fp16_t;
typedef __attribute__((ext_vector_type(8))) _Float16 fp16x8;
typedef __attribute__((ext_vector_type(4))) _Float16 fp16x4;
typedef __attribute__((ext_vector_type(2))) _Float16 fp16x2;
typedef __attribute__((ext_vector_type(4))) float f32x4;

#define WIN 512
#define NG 64

__device__ __forceinline__ void gload16(const void* g, void* l) {
    __builtin_amdgcn_global_load_lds((const __attribute__((address_space(1))) void*)g,
                                     (__attribute__((address_space(3))) void*)l, 16, 0, 0);
}

// ---------------- transpose core: fp32 src tile -> fp16 out (transposed) ----------------
// LDS stored NON-transposed [r][c] with fp16x2 vector writes (~2-way conflicts, free);
// transposed read side is scalar b16 (2-way/broadcast). 64x64 tile, 256 threads.
__device__ __forceinline__ void tr_tile(const float* __restrict__ src, int C, int srow, int scol,
                                        fp16_t* __restrict__ out, int R, int orow) {
    __shared__ fp16_t t[64][66];
    int tid = threadIdx.x;
    int tx = tid & 15, ty = tid >> 4;
#pragma unroll
    for (int j = 0; j < 4; ++j) {
        int r = ty + j * 16;
        float4 v = *(const float4*)&src[(size_t)(srow + r) * C + scol + tx * 4];
        fp16x2 a = { (fp16_t)v.x, (fp16_t)v.y };
        fp16x2 b = { (fp16_t)v.z, (fp16_t)v.w };
        *(fp16x2*)&t[r][tx * 4] = a;
        *(fp16x2*)&t[r][tx * 4 + 2] = b;
    }
    __syncthreads();
#pragma unroll
    for (int jj = 0; jj < 4; ++jj) {
        int c = ty + jj * 16;
        fp16x4 o = { t[tx * 4 + 0][c], t[tx * 4 + 1][c], t[tx * 4 + 2][c], t[tx * 4 + 3][c] };
        *(fp16x4*)&out[(size_t)(orow + c) * R + srow + tx * 4] = o;
    }
}

// merged wq|wk|wv -> wqkvT [3072][2048]
__global__ __launch_bounds__(256) void transpose_qkv3(const float* __restrict__ wq,
                                                      const float* __restrict__ wk,
                                                      const float* __restrict__ wv,
                                                      fp16_t* __restrict__ out) {
    int n0 = blockIdx.x * 64, k0 = blockIdx.y * 64;
    const float* src; int C, c0;
    if (n0 < 2048)      { src = wq; C = 2048; c0 = n0; }
    else if (n0 < 2560) { src = wk; C = 512;  c0 = n0 - 2048; }
    else                { src = wv; C = 512;  c0 = n0 - 2560; }
    tr_tile(src, C, k0, c0, out, 2048, n0);
}

// merged w1/w3 (z selects), both [2048][5632] -> [5632][2048]
__global__ __launch_bounds__(256) void transpose_w13(const float* __restrict__ w1,
                                                     const float* __restrict__ w3,
                                                     fp16_t* __restrict__ o1,
                                                     fp16_t* __restrict__ o3) {
    const float* src = blockIdx.z ? w3 : w1;
    fp16_t* out = blockIdx.z ? o3 : o1;
    tr_tile(src, 5632, blockIdx.y * 64, blockIdx.x * 64, out, 2048, blockIdx.x * 64);
}

// generic single transpose: src [*][C] -> out [C-dim rows][R]
__global__ __launch_bounds__(256) void transpose_one(const float* __restrict__ src,
                                                     fp16_t* __restrict__ out, int R, int C) {
    tr_tile(src, C, blockIdx.y * 64, blockIdx.x * 64, out, R, blockIdx.x * 64);
}

// ---------------- transpose fp16 slice [R][C] (ld,off) -> fp16 [C][R] ----------------
__global__ void transpose_b2b(const fp16_t* __restrict__ in, fp16_t* __restrict__ out,
                              int R, int C, int in_ld, int in_off) {
    __shared__ fp16_t t[32][33];
    int tx = threadIdx.x, ty = threadIdx.y;
    int c0 = blockIdx.x * 32, r0 = blockIdx.y * 32;
#pragma unroll
    for (int j = 0; j < 32; j += 8)
        t[ty + j][tx] = in[(size_t)(r0 + ty + j) * in_ld + in_off + c0 + tx];
    __syncthreads();
#pragma unroll
    for (int j = 0; j < 32; j += 8)
        out[(size_t)(c0 + ty + j) * R + r0 + tx] = t[tx][ty + j];
}

// ---------------- RMSNorm: fp32 [2048][2048] -> fp16 ----------------
__global__ __launch_bounds__(256) void rmsnorm_kernel(const float* __restrict__ in,
                                                      const float* __restrict__ g,
                                                      fp16_t* __restrict__ out) {
    int row = blockIdx.x;
    int tid = threadIdx.x;
    const float4* rp = (const float4*)(in + (size_t)row * 2048);
    float4 v0 = rp[tid], v1 = rp[tid + 256];
    float ss = v0.x * v0.x + v0.y * v0.y + v0.z * v0.z + v0.w * v0.w +
               v1.x * v1.x + v1.y * v1.y + v1.z * v1.z + v1.w * v1.w;
#pragma unroll
    for (int m = 1; m < 64; m <<= 1) ss += __shfl_xor(ss, m);
    __shared__ float red[4];
    if ((tid & 63) == 0) red[tid >> 6] = ss;
    __syncthreads();
    ss = red[0] + red[1] + red[2] + red[3];
    float sc = rsqrtf(ss * (1.0f / 2048.0f) + 1e-6f);
    const float4* gp = (const float4*)g;
    float4 g0 = gp[tid], g1 = gp[tid + 256];
    fp16x4 o0 = { (fp16_t)(v0.x * sc * g0.x), (fp16_t)(v0.y * sc * g0.y),
                  (fp16_t)(v0.z * sc * g0.z), (fp16_t)(v0.w * sc * g0.w) };
    fp16x4 o1 = { (fp16_t)(v1.x * sc * g1.x), (fp16_t)(v1.y * sc * g1.y),
                  (fp16_t)(v1.z * sc * g1.z), (fp16_t)(v1.w * sc * g1.w) };
    *(fp16x4*)(out + (size_t)row * 2048 + tid * 4) = o0;
    *(fp16x4*)(out + (size_t)row * 2048 + 1024 + tid * 4) = o1;
}

// ---------------- x1 = x + p0 + p1 (fp32), h2 = RMSNorm(x1)*g (fp16) ----------------
__global__ __launch_bounds__(256) void rmsnorm_add2(const float* __restrict__ xin,
                                                    const float* __restrict__ p0,
                                                    const float* __restrict__ p1,
                                                    const float* __restrict__ g,
                                                    float* __restrict__ x1out,
                                                    fp16_t* __restrict__ hout) {
    int row = blockIdx.x;
    int tid = threadIdx.x;
    size_t base = (size_t)row * 2048;
    const float4* xp = (const float4*)(xin + base);
    const float4* ap = (const float4*)(p0 + base);
    const float4* bp = (const float4*)(p1 + base);
    float4 v0 = xp[tid], v1 = xp[tid + 256];
    float4 a0 = ap[tid], a1 = ap[tid + 256];
    float4 b0 = bp[tid], b1 = bp[tid + 256];
    v0.x += a0.x + b0.x; v0.y += a0.y + b0.y; v0.z += a0.z + b0.z; v0.w += a0.w + b0.w;
    v1.x += a1.x + b1.x; v1.y += a1.y + b1.y; v1.z += a1.z + b1.z; v1.w += a1.w + b1.w;
    float ss = v0.x * v0.x + v0.y * v0.y + v0.z * v0.z + v0.w * v0.w +
               v1.x * v1.x + v1.y * v1.y + v1.z * v1.z + v1.w * v1.w;
#pragma unroll
    for (int m = 1; m < 64; m <<= 1) ss += __shfl_xor(ss, m);
    __shared__ float red[4];
    if ((tid & 63) == 0) red[tid >> 6] = ss;
    __syncthreads();
    ss = red[0] + red[1] + red[2] + red[3];
    float sc = rsqrtf(ss * (1.0f / 2048.0f) + 1e-6f);
    ((float4*)(x1out + base))[tid] = v0;
    ((float4*)(x1out + base))[tid + 256] = v1;
    const float4* gp = (const float4*)g;
    float4 g0 = gp[tid], g1 = gp[tid + 256];
    fp16x4 o0 = { (fp16_t)(v0.x * sc * g0.x), (fp16_t)(v0.y * sc * g0.y),
                  (fp16_t)(v0.z * sc * g0.z), (fp16_t)(v0.w * sc * g0.w) };
    fp16x4 o1 = { (fp16_t)(v1.x * sc * g1.x), (fp16_t)(v1.y * sc * g1.y),
                  (fp16_t)(v1.z * sc * g1.z), (fp16_t)(v1.w * sc * g1.w) };
    *(fp16x4*)(hout + base + tid * 4) = o0;
    *(fp16x4*)(hout + base + 1024 + tid * 4) = o1;
}

// ---------------- out += p0 + p1 (fp32, in place on d_out) ----------------
__global__ __launch_bounds__(256) void final_add2(float* __restrict__ out,
                                                  const float* __restrict__ p0,
                                                  const float* __restrict__ p1) {
    size_t i = (size_t)blockIdx.x * 256 + threadIdx.x;
    float4 o = ((const float4*)out)[i];
    float4 a = ((const float4*)p0)[i];
    float4 b = ((const float4*)p1)[i];
    o.x += a.x + b.x; o.y += a.y + b.y; o.z += a.z + b.z; o.w += a.w + b.w;
    ((float4*)out)[i] = o;
}

// ---------------- GEMM core ----------------
#define BM 128
#define BN 128
#define BKK 64

struct GemmCore {
    int tid, lane, wid, lo, hi, wr, wc;
    int arow[4], ascb[4];
    __device__ __forceinline__ void init(int t) {
        tid = t; lane = t & 63; wid = t >> 6;
        lo = lane & 15; hi = lane >> 4;
        wr = (wid >> 1) * 64; wc = (wid & 1) * 64;
#pragma unroll
        for (int p = 0; p < 4; ++p) {
            int idx = (wid * 4 + p) * 64 + lane;
            int row = idx >> 3;
            int cb = (idx & 7) << 4;
            arow[p] = row;
            ascb[p] = cb ^ ((row & 7) << 4);
        }
    }
    __device__ __forceinline__ void stage(char* buf, const fp16_t* A, const fp16_t* Bt,
                                          int brow, int bcol, int lda, int ldb, int kb) {
        char* As = buf;
        char* Bs = buf + 16384;
#pragma unroll
        for (int p = 0; p < 4; ++p) {
            int ci = wid * 4 + p;
            gload16((const char*)A + ((size_t)(brow + arow[p]) * lda + kb) * 2 + ascb[p],
                    As + ci * 1024);
            gload16((const char*)Bt + ((size_t)(bcol + arow[p]) * ldb + kb) * 2 + ascb[p],
                    Bs + ci * 1024);
        }
    }
    __device__ __forceinline__ void compute(const char* buf, f32x4 (&acc)[4][4]) {
        const char* As = buf;
        const char* Bs = buf + 16384;
#pragma unroll
        for (int kc = 0; kc < 2; ++kc) {
            fp16x8 af[4], bfr[4];
            int boff = kc * 64 + hi * 16;
#pragma unroll
            for (int m = 0; m < 4; ++m) {
                int row = wr + m * 16 + lo;
                af[m] = *(const fp16x8*)(As + row * 128 + (boff ^ ((row & 7) << 4)));
            }
#pragma unroll
            for (int n = 0; n < 4; ++n) {
                int row = wc + n * 16 + lo;
                bfr[n] = *(const fp16x8*)(Bs + row * 128 + (boff ^ ((row & 7) << 4)));
            }
#pragma unroll
            for (int m = 0; m < 4; ++m)
#pragma unroll
                for (int n = 0; n < 4; ++n)
                    acc[m][n] = __builtin_amdgcn_mfma_f32_16x16x32_f16(af[m], bfr[n], acc[m][n], 0, 0, 0);
        }
    }
};

// EPI 0: fp16 out. EPI 1: fp32 = acc + resid. EPI 2: fp32 partial at z. EPI 3: fp16 + fused QK-norm.
template <int EPI>
__global__ __launch_bounds__(256, 2) void gemm_bt(const fp16_t* __restrict__ A,
                                                  const fp16_t* __restrict__ Bt,
                                                  void* __restrict__ Cout,
                                                  const float* __restrict__ resid,
                                                  int M, int N, int K,
                                                  int lda, int ldb, int ksplit) {
    __shared__ __align__(16) char smem[2][32768];
    GemmCore g;
    g.init(threadIdx.x);
    int brow = blockIdx.y * BM, bcol = blockIdx.x * BN;

    int Kloc = K / ksplit;
    int kbase0 = blockIdx.z * Kloc;
    int nK = Kloc / BKK;

    f32x4 acc[4][4] = {};
    g.stage(smem[0], A, Bt, brow, bcol, lda, ldb, kbase0);
    __syncthreads();
    for (int kt = 0; kt < nK; ++kt) {
        if (kt + 1 < nK) g.stage(smem[(kt + 1) & 1], A, Bt, brow, bcol, lda, ldb,
                                 kbase0 + (kt + 1) * BKK);
        g.compute(smem[kt & 1], acc);
        __syncthreads();
    }

    if (EPI == 3) {
        // N-tile == one 128-dim head: bx<16 q (norm + HD^-0.5), 16..19 k (norm), 20..23 v (none)
        if (blockIdx.x < 20) {
            float* sq = (float*)smem;  // [4 wid][64 rows]
            bool isq = blockIdx.x < 16;
#pragma unroll
            for (int m = 0; m < 4; ++m)
#pragma unroll
                for (int r = 0; r < 4; ++r) {
                    float s = 0.f;
#pragma unroll
                    for (int n = 0; n < 4; ++n) s += acc[m][n][r] * acc[m][n][r];
                    s += __shfl_xor(s, 1); s += __shfl_xor(s, 2);
                    s += __shfl_xor(s, 4); s += __shfl_xor(s, 8);
                    if (g.lo == 0) sq[g.wid * 64 + m * 16 + g.hi * 4 + r] = s;
                }
            __syncthreads();
#pragma unroll
            for (int m = 0; m < 4; ++m)
#pragma unroll
                for (int r = 0; r < 4; ++r) {
                    int rl = m * 16 + g.hi * 4 + r;
                    float tot = sq[g.wid * 64 + rl] + sq[(g.wid ^ 1) * 64 + rl];
                    float sc = rsqrtf(tot * (1.0f / 128.0f) + 1e-6f);
                    if (isq) sc *= 0.08838834764831843f;
#pragma unroll
                    for (int n = 0; n < 4; ++n) acc[m][n] [r] *= sc;
                }
        }
    }

#pragma unroll
    for (int m = 0; m < 4; ++m) {
        int grow0 = brow + g.wr + m * 16 + g.hi * 4;
#pragma unroll
        for (int n = 0; n < 4; ++n) {
            int gcol = bcol + g.wc + n * 16 + g.lo;
#pragma unroll
            for (int r = 0; r < 4; ++r) {
                size_t gidx = (size_t)(grow0 + r) * N + gcol;
                float v = acc[m][n][r];
                if (EPI == 0 || EPI == 3) {
                    ((fp16_t*)Cout)[gidx] = (fp16_t)v;
                } else if (EPI == 1) {
                    ((float*)Cout)[gidx] = v + resid[gidx];
                } else {
                    ((float*)Cout)[(size_t)blockIdx.z * M * N + gidx] = v;
                }
            }
        }
    }
}

// Fused FFN up: per block, acc1 = A@w1T-tile, acc3 = A@w3T-tile (seamless prefetch across
// passes), then G = silu(acc1)*acc3 written fp16. Eliminates silu kernel + halves writes.
__global__ __launch_bounds__(256, 2) void gemm_u1u3_fused(const fp16_t* __restrict__ A,
                                                          const fp16_t* __restrict__ Bt1,
                                                          const fp16_t* __restrict__ Bt3,
                                                          fp16_t* __restrict__ G,
                                                          int M, int N, int K) {
    __shared__ __align__(16) char smem[2][32768];
    GemmCore g;
    g.init(threadIdx.x);
    int brow = blockIdx.y * BM, bcol = blockIdx.x * BN;
    int nK = K / BKK;

    f32x4 acc1[4][4] = {}, acc3[4][4] = {};
    g.stage(smem[0], A, Bt1, brow, bcol, K, K, 0);
    __syncthreads();
    for (int kt = 0; kt < nK; ++kt) {
        if (kt + 1 < nK) g.stage(smem[(kt + 1) & 1], A, Bt1, brow, bcol, K, K, (kt + 1) * BKK);
        else             g.stage(smem[(kt + 1) & 1], A, Bt3, brow, bcol, K, K, 0);
        g.compute(smem[kt & 1], acc1);
        __syncthreads();
    }
    for (int kt = 0; kt < nK; ++kt) {
        if (kt + 1 < nK) g.stage(smem[(nK + kt + 1) & 1], A, Bt3, brow, bcol, K, K, (kt + 1) * BKK);
        g.compute(smem[(nK + kt) & 1], acc3);
        __syncthreads();
    }

#pragma unroll
    for (int m = 0; m < 4; ++m) {
        int grow0 = brow + g.wr + m * 16 + g.hi * 4;
#pragma unroll
        for (int n = 0; n < 4; ++n) {
            int gcol = bcol + g.wc + n * 16 + g.lo;
#pragma unroll
            for (int r = 0; r < 4; ++r) {
                float u = acc1[m][n][r];
                float val = (u / (1.0f + __expf(-u))) * acc3[m][n][r];
                G[(size_t)(grow0 + r) * N + gcol] = (fp16_t)val;
            }
        }
    }
}

// ---------------- Flash attention: sliding-window + global, GQA 4:1 ----------------
__global__ __launch_bounds__(256, 2) void attn_kernel(const fp16_t* __restrict__ qkv,
                                                      const fp16_t* __restrict__ vT,
                                                      fp16_t* __restrict__ o) {
    __shared__ __align__(16) char smem[16384 + 16384 + 4 * 2304];
    char* Ks = smem;
    char* VTs = smem + 16384;
    char* Ps = smem + 32768;

    int t = blockIdx.x, qh = blockIdx.y;
    int kvh = qh >> 2;
    int qs = t * 64;
    int tid = threadIdx.x, lane = tid & 63, wid = tid >> 6;
    int lo = lane & 15, hi = lane >> 4;

    fp16x8 qf[4];
    {
        const fp16_t* qptr = qkv + (size_t)(qs + wid * 16 + lo) * 3072 + qh * 128 + hi * 8;
#pragma unroll
        for (int kc = 0; kc < 4; ++kc) qf[kc] = *(const fp16x8*)(qptr + kc * 32);
    }

    f32x4 oacc[8] = {};
    float m_r[4], l_r[4];
#pragma unroll
    for (int r = 0; r < 4; ++r) { m_r[r] = -1e30f; l_r[r] = 0.0f; }

    int lot = qs - (WIN - 1);
    int jt_lo = lot <= 0 ? 0 : (lot >> 6);
    int nt = (jt_lo > 0) ? (t - jt_lo + 2) : (t + 1);

    for (int ti = 0; ti < nt; ++ti) {
        int jt = (jt_lo > 0) ? (ti == 0 ? 0 : jt_lo + ti - 1) : ti;
        int js = jt * 64;
        __syncthreads();
#pragma unroll
        for (int p = 0; p < 4; ++p) {
            int ci = wid * 4 + p;
            int idx = ci * 64 + lane;
            int krow = idx >> 4;
            int kcb = (idx & 15) << 4;
            int kscb = kcb ^ ((krow & 7) << 4);
            gload16((const char*)qkv + ((size_t)(js + krow) * 3072 + 2048 + kvh * 128) * 2 + kscb,
                    Ks + ci * 1024);
            int vrow = idx >> 3;
            int vcb = (idx & 7) << 4;
            int vscb = vcb ^ ((vrow & 7) << 4);
            gload16((const char*)vT + ((size_t)(kvh * 128 + vrow) * 2048 + js) * 2 + vscb,
                    VTs + ci * 1024);
        }
        __syncthreads();

        f32x4 s[4] = {};
#pragma unroll
        for (int kc = 0; kc < 4; ++kc) {
#pragma unroll
            for (int jc = 0; jc < 4; ++jc) {
                int row = jc * 16 + lo;
                fp16x8 kf = *(const fp16x8*)(Ks + row * 256 + ((kc * 64 + hi * 16) ^ ((row & 7) << 4)));
                s[jc] = __builtin_amdgcn_mfma_f32_16x16x32_f16(qf[kc], kf, s[jc], 0, 0, 0);
            }
        }

        float mt[4] = { -1e30f, -1e30f, -1e30f, -1e30f };
#pragma unroll
        for (int jc = 0; jc < 4; ++jc) {
            int j = js + jc * 16 + lo;
#pragma unroll
            for (int r = 0; r < 4; ++r) {
                int i = qs + wid * 16 + hi * 4 + r;
                bool ok = (j <= i) && (((i - j) < WIN) || (j < NG) || (i < NG));
                float sv = ok ? s[jc][r] : -1e30f;
                s[jc][r] = sv;
                mt[r] = fmaxf(mt[r], sv);
            }
        }
#pragma unroll
        for (int m2 = 1; m2 <= 8; m2 <<= 1)
#pragma unroll
            for (int r = 0; r < 4; ++r) mt[r] = fmaxf(mt[r], __shfl_xor(mt[r], m2));
        float sf[4], psum[4];
#pragma unroll
        for (int r = 0; r < 4; ++r) {
            float mn = fmaxf(m_r[r], mt[r]);
            sf[r] = __expf(m_r[r] - mn);
            m_r[r] = mn;
            psum[r] = 0.0f;
        }
#pragma unroll
        for (int jc = 0; jc < 4; ++jc)
#pragma unroll
            for (int r = 0; r < 4; ++r) {
                float p = __expf(s[jc][r] - m_r[r]);
                s[jc][r] = p;
                psum[r] += p;
            }
#pragma unroll
        for (int m2 = 1; m2 <= 8; m2 <<= 1)
#pragma unroll
            for (int r = 0; r < 4; ++r) psum[r] += __shfl_xor(psum[r], m2);
#pragma unroll
        for (int r = 0; r < 4; ++r) l_r[r] = l_r[r] * sf[r] + psum[r];
#pragma unroll
        for (int nc = 0; nc < 8; ++nc)
#pragma unroll
            for (int r = 0; r < 4; ++r) oacc[nc][r] *= sf[r];

        char* Pb = Ps + wid * 2304;
#pragma unroll
        for (int jc = 0; jc < 4; ++jc)
#pragma unroll
            for (int r = 0; r < 4; ++r)
                *(fp16_t*)(Pb + (hi * 4 + r) * 144 + (jc * 16 + lo) * 2) = (fp16_t)s[jc][r];
        fp16x8 pa[2];
#pragma unroll
        for (int jc2 = 0; jc2 < 2; ++jc2)
            pa[jc2] = *(const fp16x8*)(Pb + lo * 144 + jc2 * 64 + hi * 16);

#pragma unroll
        for (int jc2 = 0; jc2 < 2; ++jc2)
#pragma unroll
            for (int nc = 0; nc < 8; ++nc) {
                int row = nc * 16 + lo;
                fp16x8 vf = *(const fp16x8*)(VTs + row * 128 + ((jc2 * 64 + hi * 16) ^ ((row & 7) << 4)));
                oacc[nc] = __builtin_amdgcn_mfma_f32_16x16x32_f16(pa[jc2], vf, oacc[nc], 0, 0, 0);
            }
    }

#pragma unroll
    for (int r = 0; r < 4; ++r) {
        float inv = 1.0f / l_r[r];
        int orow = qs + wid * 16 + hi * 4 + r;
#pragma unroll
        for (int nc = 0; nc < 8; ++nc)
            o[(size_t)orow * 2048 + qh * 128 + nc * 16 + lo] = (fp16_t)(oacc[nc][r] * inv);
    }
}

// ---------------- host ----------------
extern "C" void kernel_launch(void* const* d_in, const int* in_sizes, int n_in,
                              void* d_out, int out_size, void* d_ws, size_t ws_size,
                              hipStream_t stream) {
    // setup_inputs() dict order: x, g_attn, g_ffn, wq, wk, wv, wo, w1, w3, w2
    const float* x = (const float*)d_in[0];
    const float* g_attn = (const float*)d_in[1];
    const float* g_ffn = (const float*)d_in[2];
    const float* wq = (const float*)d_in[3];
    const float* wk = (const float*)d_in[4];
    const float* wv = (const float*)d_in[5];
    const float* wo = (const float*)d_in[6];
    const float* w1 = (const float*)d_in[7];  // gate proj (D,F)
    const float* w3 = (const float*)d_in[8];  // up proj   (D,F)  <- dict order!
    const float* w2 = (const float*)d_in[9];  // down proj (F,D)  <- dict order!
    float* out = (float*)d_out;               // doubles as x1 buffer

    char* ws = (char*)d_ws;
    size_t off = 0;
    auto alloc = [&](size_t bytes) {
        char* p = ws + off;
        off += (bytes + 255) & ~(size_t)255;
        return p;
    };
    // hbuf+wqkvT+vTb contiguous (8.39+12.58+2.10 = 23.07MB), all dead by FFN time
    // -> overlaid by w3T (5632*2048*2 = 23.07MB exactly).
    fp16_t* hbuf  = (fp16_t*)alloc(2048ull * 2048 * 2);  // h, then attn out o
    fp16_t* wqkvT = (fp16_t*)alloc(3072ull * 2048 * 2);  // qkv weights, then woT
    fp16_t* vTb   = (fp16_t*)alloc(512ull * 2048 * 2);
    fp16_t* qkv   = (fp16_t*)alloc(2048ull * 3072 * 2);  // qkv, then h2
    fp16_t* gbuf  = (fp16_t*)alloc(2048ull * 5632 * 2);  // g = silu(u1)*u3
    float*  part  = (float*)alloc(2ull * 2048 * 2048 * 4);  // split-K partials
    fp16_t* wbigT = (fp16_t*)alloc(5632ull * 2048 * 2);  // w1T, then w2T
    if (off > ws_size) {  // diagnostic fallback: absmax ~= max|ref|
        hipMemsetAsync(d_out, 0, (size_t)out_size * 4, stream);
        return;
    }
    float* part1 = part + 2048ull * 2048;
    fp16_t* w3T = hbuf;  // overlay (valid only after wo GEMM)

    // QKV weights -> [N][K] fp16 concat (single merged dispatch)
    transpose_qkv3<<<dim3(48, 32), 256, 0, stream>>>(wq, wk, wv, wqkvT);
    // h = RMSNorm(x) * g_attn
    rmsnorm_kernel<<<2048, 256, 0, stream>>>(x, g_attn, hbuf);
    // qkv = h @ [wq|wk|wv], with fused QK-norm (+ q * HD^-0.5) in epilogue
    gemm_bt<3><<<dim3(24, 16, 1), 256, 0, stream>>>(hbuf, wqkvT, qkv, nullptr,
                                                    2048, 3072, 2048, 2048, 2048, 1);
    // vT
    transpose_b2b<<<dim3(16, 64), dim3(32, 8), 0, stream>>>(qkv, vTb, 2048, 512, 3072, 2560);
    // attention -> o (reuses hbuf; h no longer needed)
    attn_kernel<<<dim3(32, 16), 256, 0, stream>>>(qkv, vTb, hbuf);
    // wo partials (split-K=2)
    transpose_one<<<dim3(32, 32), 256, 0, stream>>>(wo, wqkvT, 2048, 2048);
    gemm_bt<2><<<dim3(16, 16, 2), 256, 0, stream>>>(hbuf, wqkvT, part, nullptr,
                                                    2048, 2048, 2048, 2048, 2048, 2);
    // x1 = x + p0 + p1 (-> d_out); h2 = RMSNorm(x1)*g_ffn (-> qkv buffer)
    rmsnorm_add2<<<2048, 256, 0, stream>>>(x, part, part1, g_ffn, out, qkv);
    // w1,w3 transposed in one dispatch (w3T overlays dead hbuf/wqkvT/vTb)
    transpose_w13<<<dim3(88, 32, 2), 256, 0, stream>>>(w1, w3, wbigT, w3T);
    // g = silu(h2@w1) * (h2@w3), fused (acc1/acc3 per block)
    gemm_u1u3_fused<<<dim3(44, 16), 256, 0, stream>>>(qkv, wbigT, w3T, gbuf, 2048, 5632, 2048);
    // down-proj partials (split-K=2)
    transpose_one<<<dim3(32, 88), 256, 0, stream>>>(w2, wbigT, 5632, 2048);
    gemm_bt<2><<<dim3(16, 16, 2), 256, 0, stream>>>(gbuf, wbigT, part, nullptr,
                                                    2048, 2048, 5632, 5632, 5632, 2);
    // out = x1 + q0 + q1 (in place on d_out)
    final_add2<<<4096, 256, 0, stream>>>(out, part, part1);
}

// Round 8
// 306.623 us; speedup vs baseline: 1.2630x; 1.0551x over previous
//
#include <hip/hip_runtime.h>
#include <hip/hip_bf16.h>
#include <stdint.h>

typedef _Float16 fp16_t;
typedef __attribute__((ext_vector_type(8))) _Float16 fp16x8;
typedef __attribute__((ext_vector_type(4))) _Float16 fp16x4;
typedef __attribute__((ext_vector_type(2))) _Float16 fp16x2;
typedef __attribute__((ext_vector_type(4))) float f32x4;

#define WIN 512
#define NG 64

__device__ __forceinline__ void gload16(const void* g, void* l) {
    __builtin_amdgcn_global_load_lds((const __attribute__((address_space(1))) void*)g,
                                     (__attribute__((address_space(3))) void*)l, 16, 0, 0);
}

// ---------------- transpose core: fp32 src tile -> fp16 out (transposed) ----------------
__device__ __forceinline__ void tr_tile(const float* __restrict__ src, int C, int srow, int scol,
                                        fp16_t* __restrict__ out, int R, int orow) {
    __shared__ fp16_t t[64][66];
    int tid = threadIdx.x;
    int tx = tid & 15, ty = tid >> 4;
#pragma unroll
    for (int j = 0; j < 4; ++j) {
        int r = ty + j * 16;
        float4 v = *(const float4*)&src[(size_t)(srow + r) * C + scol + tx * 4];
        fp16x2 a = { (fp16_t)v.x, (fp16_t)v.y };
        fp16x2 b = { (fp16_t)v.z, (fp16_t)v.w };
        *(fp16x2*)&t[r][tx * 4] = a;
        *(fp16x2*)&t[r][tx * 4 + 2] = b;
    }
    __syncthreads();
#pragma unroll
    for (int jj = 0; jj < 4; ++jj) {
        int c = ty + jj * 16;
        fp16x4 o = { t[tx * 4 + 0][c], t[tx * 4 + 1][c], t[tx * 4 + 2][c], t[tx * 4 + 3][c] };
        *(fp16x4*)&out[(size_t)(orow + c) * R + srow + tx * 4] = o;
    }
}

// merged wq|wk|wv -> wqkvT [3072][2048]
__global__ __launch_bounds__(256) void transpose_qkv3(const float* __restrict__ wq,
                                                      const float* __restrict__ wk,
                                                      const float* __restrict__ wv,
                                                      fp16_t* __restrict__ out) {
    int n0 = blockIdx.x * 64, k0 = blockIdx.y * 64;
    const float* src; int C, c0;
    if (n0 < 2048)      { src = wq; C = 2048; c0 = n0; }
    else if (n0 < 2560) { src = wk; C = 512;  c0 = n0 - 2048; }
    else                { src = wv; C = 512;  c0 = n0 - 2560; }
    tr_tile(src, C, k0, c0, out, 2048, n0);
}

// merged w1/w3 (z selects), both [2048][5632] -> [5632][2048]
__global__ __launch_bounds__(256) void transpose_w13(const float* __restrict__ w1,
                                                     const float* __restrict__ w3,
                                                     fp16_t* __restrict__ o1,
                                                     fp16_t* __restrict__ o3) {
    const float* src = blockIdx.z ? w3 : w1;
    fp16_t* out = blockIdx.z ? o3 : o1;
    tr_tile(src, 5632, blockIdx.y * 64, blockIdx.x * 64, out, 2048, blockIdx.x * 64);
}

// generic single transpose
__global__ __launch_bounds__(256) void transpose_one(const float* __restrict__ src,
                                                     fp16_t* __restrict__ out, int R, int C) {
    tr_tile(src, C, blockIdx.y * 64, blockIdx.x * 64, out, R, blockIdx.x * 64);
}

// ---------------- RMSNorm: fp32 [2048][2048] -> fp16 ----------------
__global__ __launch_bounds__(256) void rmsnorm_kernel(const float* __restrict__ in,
                                                      const float* __restrict__ g,
                                                      fp16_t* __restrict__ out) {
    int row = blockIdx.x;
    int tid = threadIdx.x;
    const float4* rp = (const float4*)(in + (size_t)row * 2048);
    float4 v0 = rp[tid], v1 = rp[tid + 256];
    float ss = v0.x * v0.x + v0.y * v0.y + v0.z * v0.z + v0.w * v0.w +
               v1.x * v1.x + v1.y * v1.y + v1.z * v1.z + v1.w * v1.w;
#pragma unroll
    for (int m = 1; m < 64; m <<= 1) ss += __shfl_xor(ss, m);
    __shared__ float red[4];
    if ((tid & 63) == 0) red[tid >> 6] = ss;
    __syncthreads();
    ss = red[0] + red[1] + red[2] + red[3];
    float sc = rsqrtf(ss * (1.0f / 2048.0f) + 1e-6f);
    const float4* gp = (const float4*)g;
    float4 g0 = gp[tid], g1 = gp[tid + 256];
    fp16x4 o0 = { (fp16_t)(v0.x * sc * g0.x), (fp16_t)(v0.y * sc * g0.y),
                  (fp16_t)(v0.z * sc * g0.z), (fp16_t)(v0.w * sc * g0.w) };
    fp16x4 o1 = { (fp16_t)(v1.x * sc * g1.x), (fp16_t)(v1.y * sc * g1.y),
                  (fp16_t)(v1.z * sc * g1.z), (fp16_t)(v1.w * sc * g1.w) };
    *(fp16x4*)(out + (size_t)row * 2048 + tid * 4) = o0;
    *(fp16x4*)(out + (size_t)row * 2048 + 1024 + tid * 4) = o1;
}

// ---------------- x1 = x + p0 + p1 (fp32), h2 = RMSNorm(x1)*g (fp16) ----------------
__global__ __launch_bounds__(256) void rmsnorm_add2(const float* __restrict__ xin,
                                                    const float* __restrict__ p0,
                                                    const float* __restrict__ p1,
                                                    const float* __restrict__ g,
                                                    float* __restrict__ x1out,
                                                    fp16_t* __restrict__ hout) {
    int row = blockIdx.x;
    int tid = threadIdx.x;
    size_t base = (size_t)row * 2048;
    const float4* xp = (const float4*)(xin + base);
    const float4* ap = (const float4*)(p0 + base);
    const float4* bp = (const float4*)(p1 + base);
    float4 v0 = xp[tid], v1 = xp[tid + 256];
    float4 a0 = ap[tid], a1 = ap[tid + 256];
    float4 b0 = bp[tid], b1 = bp[tid + 256];
    v0.x += a0.x + b0.x; v0.y += a0.y + b0.y; v0.z += a0.z + b0.z; v0.w += a0.w + b0.w;
    v1.x += a1.x + b1.x; v1.y += a1.y + b1.y; v1.z += a1.z + b1.z; v1.w += a1.w + b1.w;
    float ss = v0.x * v0.x + v0.y * v0.y + v0.z * v0.z + v0.w * v0.w +
               v1.x * v1.x + v1.y * v1.y + v1.z * v1.z + v1.w * v1.w;
#pragma unroll
    for (int m = 1; m < 64; m <<= 1) ss += __shfl_xor(ss, m);
    __shared__ float red[4];
    if ((tid & 63) == 0) red[tid >> 6] = ss;
    __syncthreads();
    ss = red[0] + red[1] + red[2] + red[3];
    float sc = rsqrtf(ss * (1.0f / 2048.0f) + 1e-6f);
    ((float4*)(x1out + base))[tid] = v0;
    ((float4*)(x1out + base))[tid + 256] = v1;
    const float4* gp = (const float4*)g;
    float4 g0 = gp[tid], g1 = gp[tid + 256];
    fp16x4 o0 = { (fp16_t)(v0.x * sc * g0.x), (fp16_t)(v0.y * sc * g0.y),
                  (fp16_t)(v0.z * sc * g0.z), (fp16_t)(v0.w * sc * g0.w) };
    fp16x4 o1 = { (fp16_t)(v1.x * sc * g1.x), (fp16_t)(v1.y * sc * g1.y),
                  (fp16_t)(v1.z * sc * g1.z), (fp16_t)(v1.w * sc * g1.w) };
    *(fp16x4*)(hout + base + tid * 4) = o0;
    *(fp16x4*)(hout + base + 1024 + tid * 4) = o1;
}

// ---------------- out += p0 + p1 (fp32, in place on d_out) ----------------
__global__ __launch_bounds__(256) void final_add2(float* __restrict__ out,
                                                  const float* __restrict__ p0,
                                                  const float* __restrict__ p1) {
    size_t i = (size_t)blockIdx.x * 256 + threadIdx.x;
    float4 o = ((const float4*)out)[i];
    float4 a = ((const float4*)p0)[i];
    float4 b = ((const float4*)p1)[i];
    o.x += a.x + b.x; o.y += a.y + b.y; o.z += a.z + b.z; o.w += a.w + b.w;
    ((float4*)out)[i] = o;
}

// ---------------- GEMM core ----------------
#define BM 128
#define BN 128
#define BKK 64

struct GemmCore {
    int tid, lane, wid, lo, hi, wr, wc;
    int arow[4], ascb[4];
    __device__ __forceinline__ void init(int t) {
        tid = t; lane = t & 63; wid = t >> 6;
        lo = lane & 15; hi = lane >> 4;
        wr = (wid >> 1) * 64; wc = (wid & 1) * 64;
#pragma unroll
        for (int p = 0; p < 4; ++p) {
            int idx = (wid * 4 + p) * 64 + lane;
            int row = idx >> 3;
            int cb = (idx & 7) << 4;
            arow[p] = row;
            ascb[p] = cb ^ ((row & 7) << 4);
        }
    }
    __device__ __forceinline__ void stage(char* buf, const fp16_t* A, const fp16_t* Bt,
                                          int brow, int bcol, int lda, int ldb, int kb) {
        char* As = buf;
        char* Bs = buf + 16384;
#pragma unroll
        for (int p = 0; p < 4; ++p) {
            int ci = wid * 4 + p;
            gload16((const char*)A + ((size_t)(brow + arow[p]) * lda + kb) * 2 + ascb[p],
                    As + ci * 1024);
            gload16((const char*)Bt + ((size_t)(bcol + arow[p]) * ldb + kb) * 2 + ascb[p],
                    Bs + ci * 1024);
        }
    }
    __device__ __forceinline__ void compute(const char* buf, f32x4 (&acc)[4][4]) {
        const char* As = buf;
        const char* Bs = buf + 16384;
#pragma unroll
        for (int kc = 0; kc < 2; ++kc) {
            fp16x8 af[4], bfr[4];
            int boff = kc * 64 + hi * 16;
#pragma unroll
            for (int m = 0; m < 4; ++m) {
                int row = wr + m * 16 + lo;
                af[m] = *(const fp16x8*)(As + row * 128 + (boff ^ ((row & 7) << 4)));
            }
#pragma unroll
            for (int n = 0; n < 4; ++n) {
                int row = wc + n * 16 + lo;
                bfr[n] = *(const fp16x8*)(Bs + row * 128 + (boff ^ ((row & 7) << 4)));
            }
#pragma unroll
            for (int m = 0; m < 4; ++m)
#pragma unroll
                for (int n = 0; n < 4; ++n)
                    acc[m][n] = __builtin_amdgcn_mfma_f32_16x16x32_f16(af[m], bfr[n], acc[m][n], 0, 0, 0);
        }
    }
};

// EPI 0: fp16 out. EPI 1: fp32 = acc + resid. EPI 2: fp32 partial at z.
// EPI 3: fp16 + fused QK-norm; v-head blocks (bx>=20) write transposed into vT.
template <int EPI>
__global__ __launch_bounds__(256, 2) void gemm_bt(const fp16_t* __restrict__ A,
                                                  const fp16_t* __restrict__ Bt,
                                                  void* __restrict__ Cout,
                                                  const float* __restrict__ resid,
                                                  fp16_t* __restrict__ vT,
                                                  int M, int N, int K,
                                                  int lda, int ldb, int ksplit) {
    __shared__ __align__(16) char smem[2][32768];
    GemmCore g;
    g.init(threadIdx.x);
    int brow = blockIdx.y * BM, bcol = blockIdx.x * BN;

    int Kloc = K / ksplit;
    int kbase0 = blockIdx.z * Kloc;
    int nK = Kloc / BKK;

    f32x4 acc[4][4] = {};
    g.stage(smem[0], A, Bt, brow, bcol, lda, ldb, kbase0);
    __syncthreads();
    for (int kt = 0; kt < nK; ++kt) {
        if (kt + 1 < nK) g.stage(smem[(kt + 1) & 1], A, Bt, brow, bcol, lda, ldb,
                                 kbase0 + (kt + 1) * BKK);
        g.compute(smem[kt & 1], acc);
        __syncthreads();
    }

    if (EPI == 3) {
        // N-tile == one 128-dim head: bx<16 q (norm + HD^-0.5), 16..19 k (norm), 20..23 v
        if (blockIdx.x < 20) {
            float* sq = (float*)smem;  // [4 wid][64 rows]
            bool isq = blockIdx.x < 16;
#pragma unroll
            for (int m = 0; m < 4; ++m)
#pragma unroll
                for (int r = 0; r < 4; ++r) {
                    float s = 0.f;
#pragma unroll
                    for (int n = 0; n < 4; ++n) s += acc[m][n][r] * acc[m][n][r];
                    s += __shfl_xor(s, 1); s += __shfl_xor(s, 2);
                    s += __shfl_xor(s, 4); s += __shfl_xor(s, 8);
                    if (g.lo == 0) sq[g.wid * 64 + m * 16 + g.hi * 4 + r] = s;
                }
            __syncthreads();
#pragma unroll
            for (int m = 0; m < 4; ++m)
#pragma unroll
                for (int r = 0; r < 4; ++r) {
                    int rl = m * 16 + g.hi * 4 + r;
                    float tot = sq[g.wid * 64 + rl] + sq[(g.wid ^ 1) * 64 + rl];
                    float sc = rsqrtf(tot * (1.0f / 128.0f) + 1e-6f);
                    if (isq) sc *= 0.08838834764831843f;
#pragma unroll
                    for (int n = 0; n < 4; ++n) acc[m][n][r] *= sc;
                }
        } else {
            // v head: write transposed into vT [512][2048] (row = head-dim, col = token).
            // v region starts at qkv column 2560 (q:0..2047, k:2048..2559, v:2560..3071).
#pragma unroll
            for (int m = 0; m < 4; ++m) {
                int gcol0 = brow + g.wr + m * 16 + g.hi * 4;
#pragma unroll
                for (int n = 0; n < 4; ++n) {
                    int vrow = bcol + g.wc + n * 16 + g.lo - 2560;  // 0..511
                    fp16x4 o = { (fp16_t)acc[m][n][0], (fp16_t)acc[m][n][1],
                                 (fp16_t)acc[m][n][2], (fp16_t)acc[m][n][3] };
                    *(fp16x4*)&vT[(size_t)vrow * 2048 + gcol0] = o;
                }
            }
            return;
        }
    }

#pragma unroll
    for (int m = 0; m < 4; ++m) {
        int grow0 = brow + g.wr + m * 16 + g.hi * 4;
#pragma unroll
        for (int n = 0; n < 4; ++n) {
            int gcol = bcol + g.wc + n * 16 + g.lo;
#pragma unroll
            for (int r = 0; r < 4; ++r) {
                size_t gidx = (size_t)(grow0 + r) * N + gcol;
                float v = acc[m][n][r];
                if (EPI == 0 || EPI == 3) {
                    ((fp16_t*)Cout)[gidx] = (fp16_t)v;
                } else if (EPI == 1) {
                    ((float*)Cout)[gidx] = v + resid[gidx];
                } else {
                    ((float*)Cout)[(size_t)blockIdx.z * M * N + gidx] = v;
                }
            }
        }
    }
}

// Fused FFN up, half-width dual-acc: per block one 128x64 output tile of BOTH
// u1 and u3 (acc1 4x2, acc3 4x2). Staging A(16KB)+B1(8KB)+B3(8KB) per buffer;
// grid 88x16 = 1408 blocks (same TLP as the healthy dual). silu in epilogue.
__global__ __launch_bounds__(256, 2) void gemm_u1u3_half(const fp16_t* __restrict__ A,
                                                         const fp16_t* __restrict__ Bt1,
                                                         const fp16_t* __restrict__ Bt3,
                                                         fp16_t* __restrict__ G,
                                                         int M, int N, int K) {
    __shared__ __align__(16) char smem[2][32768];  // A 16K | B1 8K | B3 8K
    int tid = threadIdx.x, lane = tid & 63, wid = tid >> 6;
    int lo = lane & 15, hi = lane >> 4;
    int wr = (wid >> 1) * 64, wc = (wid & 1) * 32;
    int brow = blockIdx.y * 128, bcol = blockIdx.x * 64;
    int nK = K / BKK;

    int arow[4], ascb[4];
#pragma unroll
    for (int p = 0; p < 4; ++p) {
        int idx = (wid * 4 + p) * 64 + lane;   // 0..1023
        int row = idx >> 3;                    // 0..127
        int cb = (idx & 7) << 4;
        arow[p] = row;
        ascb[p] = cb ^ ((row & 7) << 4);
    }
    int brow_[2], bscb[2];
#pragma unroll
    for (int p = 0; p < 2; ++p) {
        int idx = (wid * 2 + p) * 64 + lane;   // 0..511
        int row = idx >> 3;                    // 0..63
        int cb = (idx & 7) << 4;
        brow_[p] = row;
        bscb[p] = cb ^ ((row & 7) << 4);
    }

    auto stage = [&](char* buf, int kb) {
        char* As = buf;
        char* B1s = buf + 16384;
        char* B3s = buf + 24576;
#pragma unroll
        for (int p = 0; p < 4; ++p)
            gload16((const char*)A + ((size_t)(brow + arow[p]) * K + kb) * 2 + ascb[p],
                    As + (wid * 4 + p) * 1024);
#pragma unroll
        for (int p = 0; p < 2; ++p) {
            gload16((const char*)Bt1 + ((size_t)(bcol + brow_[p]) * K + kb) * 2 + bscb[p],
                    B1s + (wid * 2 + p) * 1024);
            gload16((const char*)Bt3 + ((size_t)(bcol + brow_[p]) * K + kb) * 2 + bscb[p],
                    B3s + (wid * 2 + p) * 1024);
        }
    };

    f32x4 acc1[4][2] = {}, acc3[4][2] = {};
    stage(smem[0], 0);
    __syncthreads();
    for (int kt = 0; kt < nK; ++kt) {
        if (kt + 1 < nK) stage(smem[(kt + 1) & 1], (kt + 1) * BKK);
        const char* As = smem[kt & 1];
        const char* B1s = As + 16384;
        const char* B3s = As + 24576;
#pragma unroll
        for (int kc = 0; kc < 2; ++kc) {
            fp16x8 af[4], b1f[2], b3f[2];
            int boff = kc * 64 + hi * 16;
#pragma unroll
            for (int m = 0; m < 4; ++m) {
                int row = wr + m * 16 + lo;
                af[m] = *(const fp16x8*)(As + row * 128 + (boff ^ ((row & 7) << 4)));
            }
#pragma unroll
            for (int n = 0; n < 2; ++n) {
                int row = wc + n * 16 + lo;
                int o = row * 128 + (boff ^ ((row & 7) << 4));
                b1f[n] = *(const fp16x8*)(B1s + o);
                b3f[n] = *(const fp16x8*)(B3s + o);
            }
#pragma unroll
            for (int m = 0; m < 4; ++m)
#pragma unroll
                for (int n = 0; n < 2; ++n) {
                    acc1[m][n] = __builtin_amdgcn_mfma_f32_16x16x32_f16(af[m], b1f[n], acc1[m][n], 0, 0, 0);
                    acc3[m][n] = __builtin_amdgcn_mfma_f32_16x16x32_f16(af[m], b3f[n], acc3[m][n], 0, 0, 0);
                }
        }
        __syncthreads();
    }

#pragma unroll
    for (int m = 0; m < 4; ++m) {
        int grow0 = brow + wr + m * 16 + hi * 4;
#pragma unroll
        for (int n = 0; n < 2; ++n) {
            int gcol = bcol + wc + n * 16 + lo;
#pragma unroll
            for (int r = 0; r < 4; ++r) {
                float u = acc1[m][n][r];
                float val = (u / (1.0f + __expf(-u))) * acc3[m][n][r];
                G[(size_t)(grow0 + r) * N + gcol] = (fp16_t)val;
            }
        }
    }
}

// ---------------- Flash attention: sliding-window + global, GQA 4:1 ----------------
__global__ __launch_bounds__(256, 2) void attn_kernel(const fp16_t* __restrict__ qkv,
                                                      const fp16_t* __restrict__ vT,
                                                      fp16_t* __restrict__ o) {
    __shared__ __align__(16) char smem[16384 + 16384 + 4 * 2304];
    char* Ks = smem;
    char* VTs = smem + 16384;
    char* Ps = smem + 32768;

    int t = blockIdx.x, qh = blockIdx.y;
    int kvh = qh >> 2;
    int qs = t * 64;
    int tid = threadIdx.x, lane = tid & 63, wid = tid >> 6;
    int lo = lane & 15, hi = lane >> 4;

    fp16x8 qf[4];
    {
        const fp16_t* qptr = qkv + (size_t)(qs + wid * 16 + lo) * 3072 + qh * 128 + hi * 8;
#pragma unroll
        for (int kc = 0; kc < 4; ++kc) qf[kc] = *(const fp16x8*)(qptr + kc * 32);
    }

    f32x4 oacc[8] = {};
    float m_r[4], l_r[4];
#pragma unroll
    for (int r = 0; r < 4; ++r) { m_r[r] = -1e30f; l_r[r] = 0.0f; }

    int lot = qs - (WIN - 1);
    int jt_lo = lot <= 0 ? 0 : (lot >> 6);
    int nt = (jt_lo > 0) ? (t - jt_lo + 2) : (t + 1);

    for (int ti = 0; ti < nt; ++ti) {
        int jt = (jt_lo > 0) ? (ti == 0 ? 0 : jt_lo + ti - 1) : ti;
        int js = jt * 64;
        __syncthreads();
#pragma unroll
        for (int p = 0; p < 4; ++p) {
            int ci = wid * 4 + p;
            int idx = ci * 64 + lane;
            int krow = idx >> 4;
            int kcb = (idx & 15) << 4;
            int kscb = kcb ^ ((krow & 7) << 4);
            gload16((const char*)qkv + ((size_t)(js + krow) * 3072 + 2048 + kvh * 128) * 2 + kscb,
                    Ks + ci * 1024);
            int vrow = idx >> 3;
            int vcb = (idx & 7) << 4;
            int vscb = vcb ^ ((vrow & 7) << 4);
            gload16((const char*)vT + ((size_t)(kvh * 128 + vrow) * 2048 + js) * 2 + vscb,
                    VTs + ci * 1024);
        }
        __syncthreads();

        f32x4 s[4] = {};
#pragma unroll
        for (int kc = 0; kc < 4; ++kc) {
#pragma unroll
            for (int jc = 0; jc < 4; ++jc) {
                int row = jc * 16 + lo;
                fp16x8 kf = *(const fp16x8*)(Ks + row * 256 + ((kc * 64 + hi * 16) ^ ((row & 7) << 4)));
                s[jc] = __builtin_amdgcn_mfma_f32_16x16x32_f16(qf[kc], kf, s[jc], 0, 0, 0);
            }
        }

        float mt[4] = { -1e30f, -1e30f, -1e30f, -1e30f };
#pragma unroll
        for (int jc = 0; jc < 4; ++jc) {
            int j = js + jc * 16 + lo;
#pragma unroll
            for (int r = 0; r < 4; ++r) {
                int i = qs + wid * 16 + hi * 4 + r;
                bool ok = (j <= i) && (((i - j) < WIN) || (j < NG) || (i < NG));
                float sv = ok ? s[jc][r] : -1e30f;
                s[jc][r] = sv;
                mt[r] = fmaxf(mt[r], sv);
            }
        }
#pragma unroll
        for (int m2 = 1; m2 <= 8; m2 <<= 1)
#pragma unroll
            for (int r = 0; r < 4; ++r) mt[r] = fmaxf(mt[r], __shfl_xor(mt[r], m2));
        float sf[4], psum[4];
#pragma unroll
        for (int r = 0; r < 4; ++r) {
            float mn = fmaxf(m_r[r], mt[r]);
            sf[r] = __expf(m_r[r] - mn);
            m_r[r] = mn;
            psum[r] = 0.0f;
        }
#pragma unroll
        for (int jc = 0; jc < 4; ++jc)
#pragma unroll
            for (int r = 0; r < 4; ++r) {
                float p = __expf(s[jc][r] - m_r[r]);
                s[jc][r] = p;
                psum[r] += p;
            }
#pragma unroll
        for (int m2 = 1; m2 <= 8; m2 <<= 1)
#pragma unroll
            for (int r = 0; r < 4; ++r) psum[r] += __shfl_xor(psum[r], m2);
#pragma unroll
        for (int r = 0; r < 4; ++r) l_r[r] = l_r[r] * sf[r] + psum[r];
#pragma unroll
        for (int nc = 0; nc < 8; ++nc)
#pragma unroll
            for (int r = 0; r < 4; ++r) oacc[nc][r] *= sf[r];

        char* Pb = Ps + wid * 2304;
#pragma unroll
        for (int jc = 0; jc < 4; ++jc)
#pragma unroll
            for (int r = 0; r < 4; ++r)
                *(fp16_t*)(Pb + (hi * 4 + r) * 144 + (jc * 16 + lo) * 2) = (fp16_t)s[jc][r];
        fp16x8 pa[2];
#pragma unroll
        for (int jc2 = 0; jc2 < 2; ++jc2)
            pa[jc2] = *(const fp16x8*)(Pb + lo * 144 + jc2 * 64 + hi * 16);

#pragma unroll
        for (int jc2 = 0; jc2 < 2; ++jc2)
#pragma unroll
            for (int nc = 0; nc < 8; ++nc) {
                int row = nc * 16 + lo;
                fp16x8 vf = *(const fp16x8*)(VTs + row * 128 + ((jc2 * 64 + hi * 16) ^ ((row & 7) << 4)));
                oacc[nc] = __builtin_amdgcn_mfma_f32_16x16x32_f16(pa[jc2], vf, oacc[nc], 0, 0, 0);
            }
    }

#pragma unroll
    for (int r = 0; r < 4; ++r) {
        float inv = 1.0f / l_r[r];
        int orow = qs + wid * 16 + hi * 4 + r;
#pragma unroll
        for (int nc = 0; nc < 8; ++nc)
            o[(size_t)orow * 2048 + qh * 128 + nc * 16 + lo] = (fp16_t)(oacc[nc][r] * inv);
    }
}

// ---------------- host ----------------
extern "C" void kernel_launch(void* const* d_in, const int* in_sizes, int n_in,
                              void* d_out, int out_size, void* d_ws, size_t ws_size,
                              hipStream_t stream) {
    // setup_inputs() dict order: x, g_attn, g_ffn, wq, wk, wv, wo, w1, w3, w2
    const float* x = (const float*)d_in[0];
    const float* g_attn = (const float*)d_in[1];
    const float* g_ffn = (const float*)d_in[2];
    const float* wq = (const float*)d_in[3];
    const float* wk = (const float*)d_in[4];
    const float* wv = (const float*)d_in[5];
    const float* wo = (const float*)d_in[6];
    const float* w1 = (const float*)d_in[7];  // gate proj (D,F)
    const float* w3 = (const float*)d_in[8];  // up proj   (D,F)  <- dict order!
    const float* w2 = (const float*)d_in[9];  // down proj (F,D)  <- dict order!
    float* out = (float*)d_out;               // doubles as x1 buffer

    char* ws = (char*)d_ws;
    size_t off = 0;
    auto alloc = [&](size_t bytes) {
        char* p = ws + off;
        off += (bytes + 255) & ~(size_t)255;
        return p;
    };
    // hbuf+wqkvT+vTb contiguous (8.39+12.58+2.10 = 23.07MB), all dead by FFN time
    // -> overlaid by w3T (5632*2048*2 = 23.07MB exactly).
    fp16_t* hbuf  = (fp16_t*)alloc(2048ull * 2048 * 2);  // h, then attn out o
    fp16_t* wqkvT = (fp16_t*)alloc(3072ull * 2048 * 2);  // qkv weights, then woT
    fp16_t* vTb   = (fp16_t*)alloc(512ull * 2048 * 2);
    fp16_t* qkv   = (fp16_t*)alloc(2048ull * 3072 * 2);  // qkv (q|k, v unused), then h2
    fp16_t* gbuf  = (fp16_t*)alloc(2048ull * 5632 * 2);  // g = silu(u1)*u3
    float*  part  = (float*)alloc(2ull * 2048 * 2048 * 4);  // split-K partials
    fp16_t* wbigT = (fp16_t*)alloc(5632ull * 2048 * 2);  // w1T, then w2T
    if (off > ws_size) {  // diagnostic fallback: absmax ~= max|ref|
        hipMemsetAsync(d_out, 0, (size_t)out_size * 4, stream);
        return;
    }
    float* part1 = part + 2048ull * 2048;
    fp16_t* w3T = hbuf;  // overlay (valid only after wo GEMM)

    // QKV weights -> [N][K] fp16 concat (single merged dispatch)
    transpose_qkv3<<<dim3(48, 32), 256, 0, stream>>>(wq, wk, wv, wqkvT);
    // h = RMSNorm(x) * g_attn
    rmsnorm_kernel<<<2048, 256, 0, stream>>>(x, g_attn, hbuf);
    // qkv = h @ [wq|wk|wv]; fused QK-norm; v heads written transposed -> vTb
    gemm_bt<3><<<dim3(24, 16, 1), 256, 0, stream>>>(hbuf, wqkvT, qkv, nullptr, vTb,
                                                    2048, 3072, 2048, 2048, 2048, 1);
    // attention -> o (reuses hbuf; h no longer needed)
    attn_kernel<<<dim3(32, 16), 256, 0, stream>>>(qkv, vTb, hbuf);
    // wo partials (split-K=2)
    transpose_one<<<dim3(32, 32), 256, 0, stream>>>(wo, wqkvT, 2048, 2048);
    gemm_bt<2><<<dim3(16, 16, 2), 256, 0, stream>>>(hbuf, wqkvT, part, nullptr, nullptr,
                                                    2048, 2048, 2048, 2048, 2048, 2);
    // x1 = x + p0 + p1 (-> d_out); h2 = RMSNorm(x1)*g_ffn (-> qkv buffer)
    rmsnorm_add2<<<2048, 256, 0, stream>>>(x, part, part1, g_ffn, out, qkv);
    // w1,w3 transposed in one dispatch (w3T overlays dead hbuf/wqkvT/vTb)
    transpose_w13<<<dim3(88, 32, 2), 256, 0, stream>>>(w1, w3, wbigT, w3T);
    // g = silu(h2@w1) * (h2@w3), half-width dual-acc fusion (1408 blocks)
    gemm_u1u3_half<<<dim3(88, 16), 256, 0, stream>>>(qkv, wbigT, w3T, gbuf, 2048, 5632, 2048);
    // down-proj partials (split-K=2)
    transpose_one<<<dim3(32, 88), 256, 0, stream>>>(w2, wbigT, 5632, 2048);
    gemm_bt<2><<<dim3(16, 16, 2), 256, 0, stream>>>(gbuf, wbigT, part, nullptr, nullptr,
                                                    2048, 2048, 5632, 5632, 5632, 2);
    // out = x1 + q0 + q1 (in place on d_out)
    final_add2<<<4096, 256, 0, stream>>>(out, part, part1);
}

// Round 9
// 302.875 us; speedup vs baseline: 1.2787x; 1.0124x over previous
//
#include <hip/hip_runtime.h>
#include <hip/hip_bf16.h>
#include <stdint.h>

typedef _Float16 fp16_t;
typedef __attribute__((ext_vector_type(8))) _Float16 fp16x8;
typedef __attribute__((ext_vector_type(4))) _Float16 fp16x4;
typedef __attribute__((ext_vector_type(2))) _Float16 fp16x2;
typedef __attribute__((ext_vector_type(4))) float f32x4;

#define WIN 512
#define NG 64

__device__ __forceinline__ void gload16(const void* g, void* l) {
    __builtin_amdgcn_global_load_lds((const __attribute__((address_space(1))) void*)g,
                                     (__attribute__((address_space(3))) void*)l, 16, 0, 0);
}

// ---------------- transpose core: fp32 src tile -> fp16 out (transposed) ----------------
__device__ __forceinline__ void tr_tile(const float* __restrict__ src, int C, int srow, int scol,
                                        fp16_t* __restrict__ out, int R, int orow) {
    __shared__ fp16_t t[64][66];
    int tid = threadIdx.x;
    int tx = tid & 15, ty = tid >> 4;
#pragma unroll
    for (int j = 0; j < 4; ++j) {
        int r = ty + j * 16;
        float4 v = *(const float4*)&src[(size_t)(srow + r) * C + scol + tx * 4];
        fp16x2 a = { (fp16_t)v.x, (fp16_t)v.y };
        fp16x2 b = { (fp16_t)v.z, (fp16_t)v.w };
        *(fp16x2*)&t[r][tx * 4] = a;
        *(fp16x2*)&t[r][tx * 4 + 2] = b;
    }
    __syncthreads();
#pragma unroll
    for (int jj = 0; jj < 4; ++jj) {
        int c = ty + jj * 16;
        fp16x4 o = { t[tx * 4 + 0][c], t[tx * 4 + 1][c], t[tx * 4 + 2][c], t[tx * 4 + 3][c] };
        *(fp16x4*)&out[(size_t)(orow + c) * R + srow + tx * 4] = o;
    }
}

// merged wq|wk|wv -> wqkvT [3072][2048]
__global__ __launch_bounds__(256) void transpose_qkv3(const float* __restrict__ wq,
                                                      const float* __restrict__ wk,
                                                      const float* __restrict__ wv,
                                                      fp16_t* __restrict__ out) {
    int n0 = blockIdx.x * 64, k0 = blockIdx.y * 64;
    const float* src; int C, c0;
    if (n0 < 2048)      { src = wq; C = 2048; c0 = n0; }
    else if (n0 < 2560) { src = wk; C = 512;  c0 = n0 - 2048; }
    else                { src = wv; C = 512;  c0 = n0 - 2560; }
    tr_tile(src, C, k0, c0, out, 2048, n0);
}

// merged w1/w3 (z selects), both [2048][5632] -> [5632][2048]
__global__ __launch_bounds__(256) void transpose_w13(const float* __restrict__ w1,
                                                     const float* __restrict__ w3,
                                                     fp16_t* __restrict__ o1,
                                                     fp16_t* __restrict__ o3) {
    const float* src = blockIdx.z ? w3 : w1;
    fp16_t* out = blockIdx.z ? o3 : o1;
    tr_tile(src, 5632, blockIdx.y * 64, blockIdx.x * 64, out, 2048, blockIdx.x * 64);
}

// generic single transpose
__global__ __launch_bounds__(256) void transpose_one(const float* __restrict__ src,
                                                     fp16_t* __restrict__ out, int R, int C) {
    tr_tile(src, C, blockIdx.y * 64, blockIdx.x * 64, out, R, blockIdx.x * 64);
}

// ---------------- RMSNorm: fp32 [2048][2048] -> fp16 ----------------
__global__ __launch_bounds__(256) void rmsnorm_kernel(const float* __restrict__ in,
                                                      const float* __restrict__ g,
                                                      fp16_t* __restrict__ out) {
    int row = blockIdx.x;
    int tid = threadIdx.x;
    const float4* rp = (const float4*)(in + (size_t)row * 2048);
    float4 v0 = rp[tid], v1 = rp[tid + 256];
    float ss = v0.x * v0.x + v0.y * v0.y + v0.z * v0.z + v0.w * v0.w +
               v1.x * v1.x + v1.y * v1.y + v1.z * v1.z + v1.w * v1.w;
#pragma unroll
    for (int m = 1; m < 64; m <<= 1) ss += __shfl_xor(ss, m);
    __shared__ float red[4];
    if ((tid & 63) == 0) red[tid >> 6] = ss;
    __syncthreads();
    ss = red[0] + red[1] + red[2] + red[3];
    float sc = rsqrtf(ss * (1.0f / 2048.0f) + 1e-6f);
    const float4* gp = (const float4*)g;
    float4 g0 = gp[tid], g1 = gp[tid + 256];
    fp16x4 o0 = { (fp16_t)(v0.x * sc * g0.x), (fp16_t)(v0.y * sc * g0.y),
                  (fp16_t)(v0.z * sc * g0.z), (fp16_t)(v0.w * sc * g0.w) };
    fp16x4 o1 = { (fp16_t)(v1.x * sc * g1.x), (fp16_t)(v1.y * sc * g1.y),
                  (fp16_t)(v1.z * sc * g1.z), (fp16_t)(v1.w * sc * g1.w) };
    *(fp16x4*)(out + (size_t)row * 2048 + tid * 4) = o0;
    *(fp16x4*)(out + (size_t)row * 2048 + 1024 + tid * 4) = o1;
}

// ---------------- GEMM core (BM=128, BN=128) ----------------
#define BM 128
#define BN 128
#define BKK 64

struct GemmCore {
    int tid, lane, wid, lo, hi, wr, wc;
    int arow[4], ascb[4];
    __device__ __forceinline__ void init(int t) {
        tid = t; lane = t & 63; wid = t >> 6;
        lo = lane & 15; hi = lane >> 4;
        wr = (wid >> 1) * 64; wc = (wid & 1) * 64;
#pragma unroll
        for (int p = 0; p < 4; ++p) {
            int idx = (wid * 4 + p) * 64 + lane;
            int row = idx >> 3;
            int cb = (idx & 7) << 4;
            arow[p] = row;
            ascb[p] = cb ^ ((row & 7) << 4);
        }
    }
    __device__ __forceinline__ void stage(char* buf, const fp16_t* A, const fp16_t* Bt,
                                          int brow, int bcol, int lda, int ldb, int kb) {
        char* As = buf;
        char* Bs = buf + 16384;
#pragma unroll
        for (int p = 0; p < 4; ++p) {
            int ci = wid * 4 + p;
            gload16((const char*)A + ((size_t)(brow + arow[p]) * lda + kb) * 2 + ascb[p],
                    As + ci * 1024);
            gload16((const char*)Bt + ((size_t)(bcol + arow[p]) * ldb + kb) * 2 + ascb[p],
                    Bs + ci * 1024);
        }
    }
    __device__ __forceinline__ void compute(const char* buf, f32x4 (&acc)[4][4]) {
        const char* As = buf;
        const char* Bs = buf + 16384;
#pragma unroll
        for (int kc = 0; kc < 2; ++kc) {
            fp16x8 af[4], bfr[4];
            int boff = kc * 64 + hi * 16;
#pragma unroll
            for (int m = 0; m < 4; ++m) {
                int row = wr + m * 16 + lo;
                af[m] = *(const fp16x8*)(As + row * 128 + (boff ^ ((row & 7) << 4)));
            }
#pragma unroll
            for (int n = 0; n < 4; ++n) {
                int row = wc + n * 16 + lo;
                bfr[n] = *(const fp16x8*)(Bs + row * 128 + (boff ^ ((row & 7) << 4)));
            }
#pragma unroll
            for (int m = 0; m < 4; ++m)
#pragma unroll
                for (int n = 0; n < 4; ++n)
                    acc[m][n] = __builtin_amdgcn_mfma_f32_16x16x32_f16(af[m], bfr[n], acc[m][n], 0, 0, 0);
        }
    }
};

// qkv GEMM with fused QK-norm; v-head blocks (bx>=20) write transposed into vT.
__global__ __launch_bounds__(256, 2) void gemm_qkv(const fp16_t* __restrict__ A,
                                                   const fp16_t* __restrict__ Bt,
                                                   fp16_t* __restrict__ Cout,
                                                   fp16_t* __restrict__ vT,
                                                   int M, int N, int K) {
    __shared__ __align__(16) char smem[2][32768];
    GemmCore g;
    g.init(threadIdx.x);
    int brow = blockIdx.y * BM, bcol = blockIdx.x * BN;
    int nK = K / BKK;

    f32x4 acc[4][4] = {};
    g.stage(smem[0], A, Bt, brow, bcol, K, K, 0);
    __syncthreads();
    for (int kt = 0; kt < nK; ++kt) {
        if (kt + 1 < nK) g.stage(smem[(kt + 1) & 1], A, Bt, brow, bcol, K, K, (kt + 1) * BKK);
        g.compute(smem[kt & 1], acc);
        __syncthreads();
    }

    // N-tile == one 128-dim head: bx<16 q (norm + HD^-0.5), 16..19 k (norm), 20..23 v
    if (blockIdx.x < 20) {
        float* sq = (float*)smem;  // [4 wid][64 rows]
        bool isq = blockIdx.x < 16;
#pragma unroll
        for (int m = 0; m < 4; ++m)
#pragma unroll
            for (int r = 0; r < 4; ++r) {
                float s = 0.f;
#pragma unroll
                for (int n = 0; n < 4; ++n) s += acc[m][n][r] * acc[m][n][r];
                s += __shfl_xor(s, 1); s += __shfl_xor(s, 2);
                s += __shfl_xor(s, 4); s += __shfl_xor(s, 8);
                if (g.lo == 0) sq[g.wid * 64 + m * 16 + g.hi * 4 + r] = s;
            }
        __syncthreads();
#pragma unroll
        for (int m = 0; m < 4; ++m)
#pragma unroll
            for (int r = 0; r < 4; ++r) {
                int rl = m * 16 + g.hi * 4 + r;
                float tot = sq[g.wid * 64 + rl] + sq[(g.wid ^ 1) * 64 + rl];
                float sc = rsqrtf(tot * (1.0f / 128.0f) + 1e-6f);
                if (isq) sc *= 0.08838834764831843f;
#pragma unroll
                for (int n = 0; n < 4; ++n) acc[m][n][r] *= sc;
            }
#pragma unroll
        for (int m = 0; m < 4; ++m) {
            int grow0 = brow + g.wr + m * 16 + g.hi * 4;
#pragma unroll
            for (int n = 0; n < 4; ++n) {
                int gcol = bcol + g.wc + n * 16 + g.lo;
#pragma unroll
                for (int r = 0; r < 4; ++r)
                    Cout[(size_t)(grow0 + r) * N + gcol] = (fp16_t)acc[m][n][r];
            }
        }
    } else {
        // v head: transposed write into vT [512][2048]. v region starts at col 2560.
#pragma unroll
        for (int m = 0; m < 4; ++m) {
            int gcol0 = brow + g.wr + m * 16 + g.hi * 4;
#pragma unroll
            for (int n = 0; n < 4; ++n) {
                int vrow = bcol + g.wc + n * 16 + g.lo - 2560;  // 0..511
                fp16x4 o = { (fp16_t)acc[m][n][0], (fp16_t)acc[m][n][1],
                             (fp16_t)acc[m][n][2], (fp16_t)acc[m][n][3] };
                *(fp16x4*)&vT[(size_t)vrow * 2048 + gcol0] = o;
            }
        }
    }
}

// BN=64 GEMM with fused residual epilogue: Cout(fp32)[M][64-col tile] = A@Bt + resid.
// 128x64 tile, full K, 512-block grids for the two N=2048 GEMMs (no split-K partials).
__global__ __launch_bounds__(256, 2) void gemm_bt64_resid(const fp16_t* __restrict__ A,
                                                          const fp16_t* __restrict__ Bt,
                                                          float* __restrict__ Cout,
                                                          const float* __restrict__ resid,
                                                          int M, int N, int K) {
    __shared__ __align__(16) char smem[2][24576];  // A 16K | B 8K
    int tid = threadIdx.x, lane = tid & 63, wid = tid >> 6;
    int lo = lane & 15, hi = lane >> 4;
    int wr = (wid >> 1) * 64, wc = (wid & 1) * 32;
    int brow = blockIdx.y * 128, bcol = blockIdx.x * 64;
    int nK = K / BKK;

    int arow[4], ascb[4];
#pragma unroll
    for (int p = 0; p < 4; ++p) {
        int idx = (wid * 4 + p) * 64 + lane;   // 0..1023
        int row = idx >> 3;                    // 0..127
        int cb = (idx & 7) << 4;
        arow[p] = row;
        ascb[p] = cb ^ ((row & 7) << 4);
    }
    int brow_[2], bscb[2];
#pragma unroll
    for (int p = 0; p < 2; ++p) {
        int idx = (wid * 2 + p) * 64 + lane;   // 0..511
        int row = idx >> 3;                    // 0..63
        int cb = (idx & 7) << 4;
        brow_[p] = row;
        bscb[p] = cb ^ ((row & 7) << 4);
    }

    auto stage = [&](char* buf, int kb) {
        char* As = buf;
        char* Bs = buf + 16384;
#pragma unroll
        for (int p = 0; p < 4; ++p)
            gload16((const char*)A + ((size_t)(brow + arow[p]) * K + kb) * 2 + ascb[p],
                    As + (wid * 4 + p) * 1024);
#pragma unroll
        for (int p = 0; p < 2; ++p)
            gload16((const char*)Bt + ((size_t)(bcol + brow_[p]) * K + kb) * 2 + bscb[p],
                    Bs + (wid * 2 + p) * 1024);
    };

    f32x4 acc[4][2] = {};
    stage(smem[0], 0);
    __syncthreads();
    for (int kt = 0; kt < nK; ++kt) {
        if (kt + 1 < nK) stage(smem[(kt + 1) & 1], (kt + 1) * BKK);
        const char* As = smem[kt & 1];
        const char* Bs = As + 16384;
#pragma unroll
        for (int kc = 0; kc < 2; ++kc) {
            fp16x8 af[4], bfr[2];
            int boff = kc * 64 + hi * 16;
#pragma unroll
            for (int m = 0; m < 4; ++m) {
                int row = wr + m * 16 + lo;
                af[m] = *(const fp16x8*)(As + row * 128 + (boff ^ ((row & 7) << 4)));
            }
#pragma unroll
            for (int n = 0; n < 2; ++n) {
                int row = wc + n * 16 + lo;
                bfr[n] = *(const fp16x8*)(Bs + row * 128 + (boff ^ ((row & 7) << 4)));
            }
#pragma unroll
            for (int m = 0; m < 4; ++m)
#pragma unroll
                for (int n = 0; n < 2; ++n)
                    acc[m][n] = __builtin_amdgcn_mfma_f32_16x16x32_f16(af[m], bfr[n], acc[m][n], 0, 0, 0);
        }
        __syncthreads();
    }

#pragma unroll
    for (int m = 0; m < 4; ++m) {
        int grow0 = brow + wr + m * 16 + hi * 4;
#pragma unroll
        for (int n = 0; n < 2; ++n) {
            int gcol = bcol + wc + n * 16 + lo;
#pragma unroll
            for (int r = 0; r < 4; ++r) {
                size_t gidx = (size_t)(grow0 + r) * N + gcol;
                Cout[gidx] = acc[m][n][r] + resid[gidx];
            }
        }
    }
}

// Fused FFN up, half-width dual-acc (R8-verified).
__global__ __launch_bounds__(256, 2) void gemm_u1u3_half(const fp16_t* __restrict__ A,
                                                         const fp16_t* __restrict__ Bt1,
                                                         const fp16_t* __restrict__ Bt3,
                                                         fp16_t* __restrict__ G,
                                                         int M, int N, int K) {
    __shared__ __align__(16) char smem[2][32768];  // A 16K | B1 8K | B3 8K
    int tid = threadIdx.x, lane = tid & 63, wid = tid >> 6;
    int lo = lane & 15, hi = lane >> 4;
    int wr = (wid >> 1) * 64, wc = (wid & 1) * 32;
    int brow = blockIdx.y * 128, bcol = blockIdx.x * 64;
    int nK = K / BKK;

    int arow[4], ascb[4];
#pragma unroll
    for (int p = 0; p < 4; ++p) {
        int idx = (wid * 4 + p) * 64 + lane;
        int row = idx >> 3;
        int cb = (idx & 7) << 4;
        arow[p] = row;
        ascb[p] = cb ^ ((row & 7) << 4);
    }
    int brow_[2], bscb[2];
#pragma unroll
    for (int p = 0; p < 2; ++p) {
        int idx = (wid * 2 + p) * 64 + lane;
        int row = idx >> 3;
        int cb = (idx & 7) << 4;
        brow_[p] = row;
        bscb[p] = cb ^ ((row & 7) << 4);
    }

    auto stage = [&](char* buf, int kb) {
        char* As = buf;
        char* B1s = buf + 16384;
        char* B3s = buf + 24576;
#pragma unroll
        for (int p = 0; p < 4; ++p)
            gload16((const char*)A + ((size_t)(brow + arow[p]) * K + kb) * 2 + ascb[p],
                    As + (wid * 4 + p) * 1024);
#pragma unroll
        for (int p = 0; p < 2; ++p) {
            gload16((const char*)Bt1 + ((size_t)(bcol + brow_[p]) * K + kb) * 2 + bscb[p],
                    B1s + (wid * 2 + p) * 1024);
            gload16((const char*)Bt3 + ((size_t)(bcol + brow_[p]) * K + kb) * 2 + bscb[p],
                    B3s + (wid * 2 + p) * 1024);
        }
    };

    f32x4 acc1[4][2] = {}, acc3[4][2] = {};
    stage(smem[0], 0);
    __syncthreads();
    for (int kt = 0; kt < nK; ++kt) {
        if (kt + 1 < nK) stage(smem[(kt + 1) & 1], (kt + 1) * BKK);
        const char* As = smem[kt & 1];
        const char* B1s = As + 16384;
        const char* B3s = As + 24576;
#pragma unroll
        for (int kc = 0; kc < 2; ++kc) {
            fp16x8 af[4], b1f[2], b3f[2];
            int boff = kc * 64 + hi * 16;
#pragma unroll
            for (int m = 0; m < 4; ++m) {
                int row = wr + m * 16 + lo;
                af[m] = *(const fp16x8*)(As + row * 128 + (boff ^ ((row & 7) << 4)));
            }
#pragma unroll
            for (int n = 0; n < 2; ++n) {
                int row = wc + n * 16 + lo;
                int o = row * 128 + (boff ^ ((row & 7) << 4));
                b1f[n] = *(const fp16x8*)(B1s + o);
                b3f[n] = *(const fp16x8*)(B3s + o);
            }
#pragma unroll
            for (int m = 0; m < 4; ++m)
#pragma unroll
                for (int n = 0; n < 2; ++n) {
                    acc1[m][n] = __builtin_amdgcn_mfma_f32_16x16x32_f16(af[m], b1f[n], acc1[m][n], 0, 0, 0);
                    acc3[m][n] = __builtin_amdgcn_mfma_f32_16x16x32_f16(af[m], b3f[n], acc3[m][n], 0, 0, 0);
                }
        }
        __syncthreads();
    }

#pragma unroll
    for (int m = 0; m < 4; ++m) {
        int grow0 = brow + wr + m * 16 + hi * 4;
#pragma unroll
        for (int n = 0; n < 2; ++n) {
            int gcol = bcol + wc + n * 16 + lo;
#pragma unroll
            for (int r = 0; r < 4; ++r) {
                float u = acc1[m][n][r];
                float val = (u / (1.0f + __expf(-u))) * acc3[m][n][r];
                G[(size_t)(grow0 + r) * N + gcol] = (fp16_t)val;
            }
        }
    }
}

// ---------------- Flash attention: sliding-window + global, GQA 4:1 ----------------
__global__ __launch_bounds__(256, 2) void attn_kernel(const fp16_t* __restrict__ qkv,
                                                      const fp16_t* __restrict__ vT,
                                                      fp16_t* __restrict__ o) {
    __shared__ __align__(16) char smem[16384 + 16384 + 4 * 2304];
    char* Ks = smem;
    char* VTs = smem + 16384;
    char* Ps = smem + 32768;

    int t = blockIdx.x, qh = blockIdx.y;
    int kvh = qh >> 2;
    int qs = t * 64;
    int tid = threadIdx.x, lane = tid & 63, wid = tid >> 6;
    int lo = lane & 15, hi = lane >> 4;

    fp16x8 qf[4];
    {
        const fp16_t* qptr = qkv + (size_t)(qs + wid * 16 + lo) * 3072 + qh * 128 + hi * 8;
#pragma unroll
        for (int kc = 0; kc < 4; ++kc) qf[kc] = *(const fp16x8*)(qptr + kc * 32);
    }

    f32x4 oacc[8] = {};
    float m_r[4], l_r[4];
#pragma unroll
    for (int r = 0; r < 4; ++r) { m_r[r] = -1e30f; l_r[r] = 0.0f; }

    int lot = qs - (WIN - 1);
    int jt_lo = lot <= 0 ? 0 : (lot >> 6);
    int nt = (jt_lo > 0) ? (t - jt_lo + 2) : (t + 1);

    for (int ti = 0; ti < nt; ++ti) {
        int jt = (jt_lo > 0) ? (ti == 0 ? 0 : jt_lo + ti - 1) : ti;
        int js = jt * 64;
        __syncthreads();
#pragma unroll
        for (int p = 0; p < 4; ++p) {
            int ci = wid * 4 + p;
            int idx = ci * 64 + lane;
            int krow = idx >> 4;
            int kcb = (idx & 15) << 4;
            int kscb = kcb ^ ((krow & 7) << 4);
            gload16((const char*)qkv + ((size_t)(js + krow) * 3072 + 2048 + kvh * 128) * 2 + kscb,
                    Ks + ci * 1024);
            int vrow = idx >> 3;
            int vcb = (idx & 7) << 4;
            int vscb = vcb ^ ((vrow & 7) << 4);
            gload16((const char*)vT + ((size_t)(kvh * 128 + vrow) * 2048 + js) * 2 + vscb,
                    VTs + ci * 1024);
        }
        __syncthreads();

        f32x4 s[4] = {};
#pragma unroll
        for (int kc = 0; kc < 4; ++kc) {
#pragma unroll
            for (int jc = 0; jc < 4; ++jc) {
                int row = jc * 16 + lo;
                fp16x8 kf = *(const fp16x8*)(Ks + row * 256 + ((kc * 64 + hi * 16) ^ ((row & 7) << 4)));
                s[jc] = __builtin_amdgcn_mfma_f32_16x16x32_f16(qf[kc], kf, s[jc], 0, 0, 0);
            }
        }

        float mt[4] = { -1e30f, -1e30f, -1e30f, -1e30f };
#pragma unroll
        for (int jc = 0; jc < 4; ++jc) {
            int j = js + jc * 16 + lo;
#pragma unroll
            for (int r = 0; r < 4; ++r) {
                int i = qs + wid * 16 + hi * 4 + r;
                bool ok = (j <= i) && (((i - j) < WIN) || (j < NG) || (i < NG));
                float sv = ok ? s[jc][r] : -1e30f;
                s[jc][r] = sv;
                mt[r] = fmaxf(mt[r], sv);
            }
        }
#pragma unroll
        for (int m2 = 1; m2 <= 8; m2 <<= 1)
#pragma unroll
            for (int r = 0; r < 4; ++r) mt[r] = fmaxf(mt[r], __shfl_xor(mt[r], m2));
        float sf[4], psum[4];
#pragma unroll
        for (int r = 0; r < 4; ++r) {
            float mn = fmaxf(m_r[r], mt[r]);
            sf[r] = __expf(m_r[r] - mn);
            m_r[r] = mn;
            psum[r] = 0.0f;
        }
#pragma unroll
        for (int jc = 0; jc < 4; ++jc)
#pragma unroll
            for (int r = 0; r < 4; ++r) {
                float p = __expf(s[jc][r] - m_r[r]);
                s[jc][r] = p;
                psum[r] += p;
            }
#pragma unroll
        for (int m2 = 1; m2 <= 8; m2 <<= 1)
#pragma unroll
            for (int r = 0; r < 4; ++r) psum[r] += __shfl_xor(psum[r], m2);
#pragma unroll
        for (int r = 0; r < 4; ++r) l_r[r] = l_r[r] * sf[r] + psum[r];
#pragma unroll
        for (int nc = 0; nc < 8; ++nc)
#pragma unroll
            for (int r = 0; r < 4; ++r) oacc[nc][r] *= sf[r];

        char* Pb = Ps + wid * 2304;
#pragma unroll
        for (int jc = 0; jc < 4; ++jc)
#pragma unroll
            for (int r = 0; r < 4; ++r)
                *(fp16_t*)(Pb + (hi * 4 + r) * 144 + (jc * 16 + lo) * 2) = (fp16_t)s[jc][r];
        fp16x8 pa[2];
#pragma unroll
        for (int jc2 = 0; jc2 < 2; ++jc2)
            pa[jc2] = *(const fp16x8*)(Pb + lo * 144 + jc2 * 64 + hi * 16);

#pragma unroll
        for (int jc2 = 0; jc2 < 2; ++jc2)
#pragma unroll
            for (int nc = 0; nc < 8; ++nc) {
                int row = nc * 16 + lo;
                fp16x8 vf = *(const fp16x8*)(VTs + row * 128 + ((jc2 * 64 + hi * 16) ^ ((row & 7) << 4)));
                oacc[nc] = __builtin_amdgcn_mfma_f32_16x16x32_f16(pa[jc2], vf, oacc[nc], 0, 0, 0);
            }
    }

#pragma unroll
    for (int r = 0; r < 4; ++r) {
        float inv = 1.0f / l_r[r];
        int orow = qs + wid * 16 + hi * 4 + r;
#pragma unroll
        for (int nc = 0; nc < 8; ++nc)
            o[(size_t)orow * 2048 + qh * 128 + nc * 16 + lo] = (fp16_t)(oacc[nc][r] * inv);
    }
}

// ---------------- host ----------------
extern "C" void kernel_launch(void* const* d_in, const int* in_sizes, int n_in,
                              void* d_out, int out_size, void* d_ws, size_t ws_size,
                              hipStream_t stream) {
    // setup_inputs() dict order: x, g_attn, g_ffn, wq, wk, wv, wo, w1, w3, w2
    const float* x = (const float*)d_in[0];
    const float* g_attn = (const float*)d_in[1];
    const float* g_ffn = (const float*)d_in[2];
    const float* wq = (const float*)d_in[3];
    const float* wk = (const float*)d_in[4];
    const float* wv = (const float*)d_in[5];
    const float* wo = (const float*)d_in[6];
    const float* w1 = (const float*)d_in[7];  // gate proj (D,F)
    const float* w3 = (const float*)d_in[8];  // up proj   (D,F)  <- dict order!
    const float* w2 = (const float*)d_in[9];  // down proj (F,D)  <- dict order!
    float* out = (float*)d_out;               // doubles as x1 buffer

    char* ws = (char*)d_ws;
    size_t off = 0;
    auto alloc = [&](size_t bytes) {
        char* p = ws + off;
        off += (bytes + 255) & ~(size_t)255;
        return p;
    };
    // hbuf+wqkvT+vTb contiguous (8.39+12.58+2.10 = 23.07MB), all dead by FFN time
    // -> overlaid by w3T (5632*2048*2 = 23.07MB exactly).
    fp16_t* hbuf  = (fp16_t*)alloc(2048ull * 2048 * 2);  // h, then attn out o
    fp16_t* wqkvT = (fp16_t*)alloc(3072ull * 2048 * 2);  // qkv weights, then woT
    fp16_t* vTb   = (fp16_t*)alloc(512ull * 2048 * 2);
    fp16_t* qkv   = (fp16_t*)alloc(2048ull * 3072 * 2);  // q|k (v direct to vTb), then h2
    fp16_t* gbuf  = (fp16_t*)alloc(2048ull * 5632 * 2);  // g = silu(u1)*u3
    fp16_t* wbigT = (fp16_t*)alloc(5632ull * 2048 * 2);  // w1T, then w2T
    if (off > ws_size) {  // diagnostic fallback: absmax ~= max|ref|
        hipMemsetAsync(d_out, 0, (size_t)out_size * 4, stream);
        return;
    }
    fp16_t* w3T = hbuf;  // overlay (valid only after wo GEMM)

    // QKV weights -> [N][K] fp16 concat (single merged dispatch)
    transpose_qkv3<<<dim3(48, 32), 256, 0, stream>>>(wq, wk, wv, wqkvT);
    // h = RMSNorm(x) * g_attn
    rmsnorm_kernel<<<2048, 256, 0, stream>>>(x, g_attn, hbuf);
    // qkv = h @ [wq|wk|wv]; fused QK-norm; v heads written transposed -> vTb
    gemm_qkv<<<dim3(24, 16), 256, 0, stream>>>(hbuf, wqkvT, qkv, vTb, 2048, 3072, 2048);
    // attention -> o (reuses hbuf; h no longer needed)
    attn_kernel<<<dim3(32, 16), 256, 0, stream>>>(qkv, vTb, hbuf);
    // x1 = x + o @ wo  (BN=64, 512 blocks, fused residual, fp32 -> d_out)
    transpose_one<<<dim3(32, 32), 256, 0, stream>>>(wo, wqkvT, 2048, 2048);
    gemm_bt64_resid<<<dim3(32, 16), 256, 0, stream>>>(hbuf, wqkvT, out, x, 2048, 2048, 2048);
    // h2 = RMSNorm(x1) * g_ffn  (-> qkv buffer)
    rmsnorm_kernel<<<2048, 256, 0, stream>>>(out, g_ffn, qkv);
    // w1,w3 transposed in one dispatch (w3T overlays dead hbuf/wqkvT/vTb)
    transpose_w13<<<dim3(88, 32, 2), 256, 0, stream>>>(w1, w3, wbigT, w3T);
    // g = silu(h2@w1) * (h2@w3), half-width dual-acc fusion (1408 blocks)
    gemm_u1u3_half<<<dim3(88, 16), 256, 0, stream>>>(qkv, wbigT, w3T, gbuf, 2048, 5632, 2048);
    // out = x1 + g @ w2  (BN=64, 512 blocks, fused residual, in-place on d_out)
    transpose_one<<<dim3(32, 88), 256, 0, stream>>>(w2, wbigT, 5632, 2048);
    gemm_bt64_resid<<<dim3(32, 16), 256, 0, stream>>>(gbuf, wbigT, out, out, 2048, 2048, 5632);
}

// Round 10
// 295.298 us; speedup vs baseline: 1.3115x; 1.0257x over previous
//
#include <hip/hip_runtime.h>
#include <hip/hip_bf16.h>
#include <stdint.h>

typedef _Float16 fp16_t;
typedef __attribute__((ext_vector_type(8))) _Float16 fp16x8;
typedef __attribute__((ext_vector_type(4))) _Float16 fp16x4;
typedef __attribute__((ext_vector_type(2))) _Float16 fp16x2;
typedef __attribute__((ext_vector_type(4))) float f32x4;

#define WIN 512
#define NG 64

__device__ __forceinline__ void gload16(const void* g, void* l) {
    __builtin_amdgcn_global_load_lds((const __attribute__((address_space(1))) void*)g,
                                     (__attribute__((address_space(3))) void*)l, 16, 0, 0);
}

// counted vmcnt waits (T4): keep newest stage's loads in flight across barriers
__device__ __forceinline__ void wait_vm8() { asm volatile("s_waitcnt vmcnt(8)" ::: "memory"); }
__device__ __forceinline__ void wait_vm6() { asm volatile("s_waitcnt vmcnt(6)" ::: "memory"); }
__device__ __forceinline__ void wait_vm0() { asm volatile("s_waitcnt vmcnt(0)" ::: "memory"); }

// ---------------- transpose core: fp32 src tile -> fp16 out (transposed) ----------------
__device__ __forceinline__ void tr_tile(const float* __restrict__ src, int C, int srow, int scol,
                                        fp16_t* __restrict__ out, int R, int orow) {
    __shared__ fp16_t t[64][66];
    int tid = threadIdx.x;
    int tx = tid & 15, ty = tid >> 4;
#pragma unroll
    for (int j = 0; j < 4; ++j) {
        int r = ty + j * 16;
        float4 v = *(const float4*)&src[(size_t)(srow + r) * C + scol + tx * 4];
        fp16x2 a = { (fp16_t)v.x, (fp16_t)v.y };
        fp16x2 b = { (fp16_t)v.z, (fp16_t)v.w };
        *(fp16x2*)&t[r][tx * 4] = a;
        *(fp16x2*)&t[r][tx * 4 + 2] = b;
    }
    __syncthreads();
#pragma unroll
    for (int jj = 0; jj < 4; ++jj) {
        int c = ty + jj * 16;
        fp16x4 o = { t[tx * 4 + 0][c], t[tx * 4 + 1][c], t[tx * 4 + 2][c], t[tx * 4 + 3][c] };
        *(fp16x4*)&out[(size_t)(orow + c) * R + srow + tx * 4] = o;
    }
}

// merged wq|wk|wv -> wqkvT [3072][2048]
__global__ __launch_bounds__(256) void transpose_qkv3(const float* __restrict__ wq,
                                                      const float* __restrict__ wk,
                                                      const float* __restrict__ wv,
                                                      fp16_t* __restrict__ out) {
    int n0 = blockIdx.x * 64, k0 = blockIdx.y * 64;
    const float* src; int C, c0;
    if (n0 < 2048)      { src = wq; C = 2048; c0 = n0; }
    else if (n0 < 2560) { src = wk; C = 512;  c0 = n0 - 2048; }
    else                { src = wv; C = 512;  c0 = n0 - 2560; }
    tr_tile(src, C, k0, c0, out, 2048, n0);
}

// merged w1/w3 (z selects), both [2048][5632] -> [5632][2048]
__global__ __launch_bounds__(256) void transpose_w13(const float* __restrict__ w1,
                                                     const float* __restrict__ w3,
                                                     fp16_t* __restrict__ o1,
                                                     fp16_t* __restrict__ o3) {
    const float* src = blockIdx.z ? w3 : w1;
    fp16_t* out = blockIdx.z ? o3 : o1;
    tr_tile(src, 5632, blockIdx.y * 64, blockIdx.x * 64, out, 2048, blockIdx.x * 64);
}

// generic single transpose
__global__ __launch_bounds__(256) void transpose_one(const float* __restrict__ src,
                                                     fp16_t* __restrict__ out, int R, int C) {
    tr_tile(src, C, blockIdx.y * 64, blockIdx.x * 64, out, R, blockIdx.x * 64);
}

// ---------------- RMSNorm: fp32 [2048][2048] -> fp16 ----------------
__global__ __launch_bounds__(256) void rmsnorm_kernel(const float* __restrict__ in,
                                                      const float* __restrict__ g,
                                                      fp16_t* __restrict__ out) {
    int row = blockIdx.x;
    int tid = threadIdx.x;
    const float4* rp = (const float4*)(in + (size_t)row * 2048);
    float4 v0 = rp[tid], v1 = rp[tid + 256];
    float ss = v0.x * v0.x + v0.y * v0.y + v0.z * v0.z + v0.w * v0.w +
               v1.x * v1.x + v1.y * v1.y + v1.z * v1.z + v1.w * v1.w;
#pragma unroll
    for (int m = 1; m < 64; m <<= 1) ss += __shfl_xor(ss, m);
    __shared__ float red[4];
    if ((tid & 63) == 0) red[tid >> 6] = ss;
    __syncthreads();
    ss = red[0] + red[1] + red[2] + red[3];
    float sc = rsqrtf(ss * (1.0f / 2048.0f) + 1e-6f);
    const float4* gp = (const float4*)g;
    float4 g0 = gp[tid], g1 = gp[tid + 256];
    fp16x4 o0 = { (fp16_t)(v0.x * sc * g0.x), (fp16_t)(v0.y * sc * g0.y),
                  (fp16_t)(v0.z * sc * g0.z), (fp16_t)(v0.w * sc * g0.w) };
    fp16x4 o1 = { (fp16_t)(v1.x * sc * g1.x), (fp16_t)(v1.y * sc * g1.y),
                  (fp16_t)(v1.z * sc * g1.z), (fp16_t)(v1.w * sc * g1.w) };
    *(fp16x4*)(out + (size_t)row * 2048 + tid * 4) = o0;
    *(fp16x4*)(out + (size_t)row * 2048 + 1024 + tid * 4) = o1;
}

// ---------------- GEMM core (BM=128, BN=128) ----------------
#define BM 128
#define BN 128
#define BKK 64

struct GemmCore {
    int tid, lane, wid, lo, hi, wr, wc;
    int arow[4], ascb[4];
    __device__ __forceinline__ void init(int t) {
        tid = t; lane = t & 63; wid = t >> 6;
        lo = lane & 15; hi = lane >> 4;
        wr = (wid >> 1) * 64; wc = (wid & 1) * 64;
#pragma unroll
        for (int p = 0; p < 4; ++p) {
            int idx = (wid * 4 + p) * 64 + lane;
            int row = idx >> 3;
            int cb = (idx & 7) << 4;
            arow[p] = row;
            ascb[p] = cb ^ ((row & 7) << 4);
        }
    }
    __device__ __forceinline__ void stage(char* buf, const fp16_t* A, const fp16_t* Bt,
                                          int brow, int bcol, int lda, int ldb, int kb) {
        char* As = buf;
        char* Bs = buf + 16384;
#pragma unroll
        for (int p = 0; p < 4; ++p) {
            int ci = wid * 4 + p;
            gload16((const char*)A + ((size_t)(brow + arow[p]) * lda + kb) * 2 + ascb[p],
                    As + ci * 1024);
            gload16((const char*)Bt + ((size_t)(bcol + arow[p]) * ldb + kb) * 2 + ascb[p],
                    Bs + ci * 1024);
        }
    }
    __device__ __forceinline__ void compute(const char* buf, f32x4 (&acc)[4][4]) {
        const char* As = buf;
        const char* Bs = buf + 16384;
#pragma unroll
        for (int kc = 0; kc < 2; ++kc) {
            fp16x8 af[4], bfr[4];
            int boff = kc * 64 + hi * 16;
#pragma unroll
            for (int m = 0; m < 4; ++m) {
                int row = wr + m * 16 + lo;
                af[m] = *(const fp16x8*)(As + row * 128 + (boff ^ ((row & 7) << 4)));
            }
#pragma unroll
            for (int n = 0; n < 4; ++n) {
                int row = wc + n * 16 + lo;
                bfr[n] = *(const fp16x8*)(Bs + row * 128 + (boff ^ ((row & 7) << 4)));
            }
#pragma unroll
            for (int m = 0; m < 4; ++m)
#pragma unroll
                for (int n = 0; n < 4; ++n)
                    acc[m][n] = __builtin_amdgcn_mfma_f32_16x16x32_f16(af[m], bfr[n], acc[m][n], 0, 0, 0);
        }
    }
};

// qkv GEMM with fused QK-norm; v-head blocks (bx>=20) write transposed into vT.
// Pipelined loop: counted vmcnt(8) + raw barriers (stage(t+1) stays in flight).
__global__ __launch_bounds__(256, 2) void gemm_qkv(const fp16_t* __restrict__ A,
                                                   const fp16_t* __restrict__ Bt,
                                                   fp16_t* __restrict__ Cout,
                                                   fp16_t* __restrict__ vT,
                                                   int M, int N, int K) {
    __shared__ __align__(16) char smem[2][32768];
    GemmCore g;
    g.init(threadIdx.x);
    int brow = blockIdx.y * BM, bcol = blockIdx.x * BN;
    int nK = K / BKK;

    f32x4 acc[4][4] = {};
    g.stage(smem[0], A, Bt, brow, bcol, K, K, 0);
    for (int kt = 0; kt < nK; ++kt) {
        if (kt + 1 < nK) {
            g.stage(smem[(kt + 1) & 1], A, Bt, brow, bcol, K, K, (kt + 1) * BKK);
            wait_vm8();          // stage(kt) complete; stage(kt+1)'s 8 loads stay in flight
        } else {
            wait_vm0();
        }
        __builtin_amdgcn_s_barrier();
        __builtin_amdgcn_sched_barrier(0);
        g.compute(smem[kt & 1], acc);
        __builtin_amdgcn_s_barrier();   // protect buf[kt] from next iter's stage(kt+2)
    }

    // N-tile == one 128-dim head: bx<16 q (norm + HD^-0.5), 16..19 k (norm), 20..23 v
    if (blockIdx.x < 20) {
        float* sq = (float*)smem;  // [4 wid][64 rows]
        bool isq = blockIdx.x < 16;
#pragma unroll
        for (int m = 0; m < 4; ++m)
#pragma unroll
            for (int r = 0; r < 4; ++r) {
                float s = 0.f;
#pragma unroll
                for (int n = 0; n < 4; ++n) s += acc[m][n][r] * acc[m][n][r];
                s += __shfl_xor(s, 1); s += __shfl_xor(s, 2);
                s += __shfl_xor(s, 4); s += __shfl_xor(s, 8);
                if (g.lo == 0) sq[g.wid * 64 + m * 16 + g.hi * 4 + r] = s;
            }
        __syncthreads();
#pragma unroll
        for (int m = 0; m < 4; ++m)
#pragma unroll
            for (int r = 0; r < 4; ++r) {
                int rl = m * 16 + g.hi * 4 + r;
                float tot = sq[g.wid * 64 + rl] + sq[(g.wid ^ 1) * 64 + rl];
                float sc = rsqrtf(tot * (1.0f / 128.0f) + 1e-6f);
                if (isq) sc *= 0.08838834764831843f;
#pragma unroll
                for (int n = 0; n < 4; ++n) acc[m][n][r] *= sc;
            }
#pragma unroll
        for (int m = 0; m < 4; ++m) {
            int grow0 = brow + g.wr + m * 16 + g.hi * 4;
#pragma unroll
            for (int n = 0; n < 4; ++n) {
                int gcol = bcol + g.wc + n * 16 + g.lo;
#pragma unroll
                for (int r = 0; r < 4; ++r)
                    Cout[(size_t)(grow0 + r) * N + gcol] = (fp16_t)acc[m][n][r];
            }
        }
    } else {
        // v head: transposed write into vT [512][2048]. v region starts at col 2560.
#pragma unroll
        for (int m = 0; m < 4; ++m) {
            int gcol0 = brow + g.wr + m * 16 + g.hi * 4;
#pragma unroll
            for (int n = 0; n < 4; ++n) {
                int vrow = bcol + g.wc + n * 16 + g.lo - 2560;  // 0..511
                fp16x4 o = { (fp16_t)acc[m][n][0], (fp16_t)acc[m][n][1],
                             (fp16_t)acc[m][n][2], (fp16_t)acc[m][n][3] };
                *(fp16x4*)&vT[(size_t)vrow * 2048 + gcol0] = o;
            }
        }
    }
}

// BN=64 GEMM with fused residual epilogue (pipelined: vmcnt(6) + raw barriers).
__global__ __launch_bounds__(256, 2) void gemm_bt64_resid(const fp16_t* __restrict__ A,
                                                          const fp16_t* __restrict__ Bt,
                                                          float* __restrict__ Cout,
                                                          const float* __restrict__ resid,
                                                          int M, int N, int K) {
    __shared__ __align__(16) char smem[2][24576];  // A 16K | B 8K
    int tid = threadIdx.x, lane = tid & 63, wid = tid >> 6;
    int lo = lane & 15, hi = lane >> 4;
    int wr = (wid >> 1) * 64, wc = (wid & 1) * 32;
    int brow = blockIdx.y * 128, bcol = blockIdx.x * 64;
    int nK = K / BKK;

    int arow[4], ascb[4];
#pragma unroll
    for (int p = 0; p < 4; ++p) {
        int idx = (wid * 4 + p) * 64 + lane;   // 0..1023
        int row = idx >> 3;                    // 0..127
        int cb = (idx & 7) << 4;
        arow[p] = row;
        ascb[p] = cb ^ ((row & 7) << 4);
    }
    int brow_[2], bscb[2];
#pragma unroll
    for (int p = 0; p < 2; ++p) {
        int idx = (wid * 2 + p) * 64 + lane;   // 0..511
        int row = idx >> 3;                    // 0..63
        int cb = (idx & 7) << 4;
        brow_[p] = row;
        bscb[p] = cb ^ ((row & 7) << 4);
    }

    auto stage = [&](char* buf, int kb) {
        char* As = buf;
        char* Bs = buf + 16384;
#pragma unroll
        for (int p = 0; p < 4; ++p)
            gload16((const char*)A + ((size_t)(brow + arow[p]) * K + kb) * 2 + ascb[p],
                    As + (wid * 4 + p) * 1024);
#pragma unroll
        for (int p = 0; p < 2; ++p)
            gload16((const char*)Bt + ((size_t)(bcol + brow_[p]) * K + kb) * 2 + bscb[p],
                    Bs + (wid * 2 + p) * 1024);
    };

    f32x4 acc[4][2] = {};
    stage(smem[0], 0);
    for (int kt = 0; kt < nK; ++kt) {
        if (kt + 1 < nK) {
            stage(smem[(kt + 1) & 1], (kt + 1) * BKK);
            wait_vm6();
        } else {
            wait_vm0();
        }
        __builtin_amdgcn_s_barrier();
        __builtin_amdgcn_sched_barrier(0);
        const char* As = smem[kt & 1];
        const char* Bs = As + 16384;
#pragma unroll
        for (int kc = 0; kc < 2; ++kc) {
            fp16x8 af[4], bfr[2];
            int boff = kc * 64 + hi * 16;
#pragma unroll
            for (int m = 0; m < 4; ++m) {
                int row = wr + m * 16 + lo;
                af[m] = *(const fp16x8*)(As + row * 128 + (boff ^ ((row & 7) << 4)));
            }
#pragma unroll
            for (int n = 0; n < 2; ++n) {
                int row = wc + n * 16 + lo;
                bfr[n] = *(const fp16x8*)(Bs + row * 128 + (boff ^ ((row & 7) << 4)));
            }
#pragma unroll
            for (int m = 0; m < 4; ++m)
#pragma unroll
                for (int n = 0; n < 2; ++n)
                    acc[m][n] = __builtin_amdgcn_mfma_f32_16x16x32_f16(af[m], bfr[n], acc[m][n], 0, 0, 0);
        }
        __builtin_amdgcn_s_barrier();
    }

#pragma unroll
    for (int m = 0; m < 4; ++m) {
        int grow0 = brow + wr + m * 16 + hi * 4;
#pragma unroll
        for (int n = 0; n < 2; ++n) {
            int gcol = bcol + wc + n * 16 + lo;
#pragma unroll
            for (int r = 0; r < 4; ++r) {
                size_t gidx = (size_t)(grow0 + r) * N + gcol;
                Cout[gidx] = acc[m][n][r] + resid[gidx];
            }
        }
    }
}

// Fused FFN up, half-width dual-acc (pipelined: vmcnt(8) + raw barriers).
__global__ __launch_bounds__(256, 2) void gemm_u1u3_half(const fp16_t* __restrict__ A,
                                                         const fp16_t* __restrict__ Bt1,
                                                         const fp16_t* __restrict__ Bt3,
                                                         fp16_t* __restrict__ G,
                                                         int M, int N, int K) {
    __shared__ __align__(16) char smem[2][32768];  // A 16K | B1 8K | B3 8K
    int tid = threadIdx.x, lane = tid & 63, wid = tid >> 6;
    int lo = lane & 15, hi = lane >> 4;
    int wr = (wid >> 1) * 64, wc = (wid & 1) * 32;
    int brow = blockIdx.y * 128, bcol = blockIdx.x * 64;
    int nK = K / BKK;

    int arow[4], ascb[4];
#pragma unroll
    for (int p = 0; p < 4; ++p) {
        int idx = (wid * 4 + p) * 64 + lane;
        int row = idx >> 3;
        int cb = (idx & 7) << 4;
        arow[p] = row;
        ascb[p] = cb ^ ((row & 7) << 4);
    }
    int brow_[2], bscb[2];
#pragma unroll
    for (int p = 0; p < 2; ++p) {
        int idx = (wid * 2 + p) * 64 + lane;
        int row = idx >> 3;
        int cb = (idx & 7) << 4;
        brow_[p] = row;
        bscb[p] = cb ^ ((row & 7) << 4);
    }

    auto stage = [&](char* buf, int kb) {
        char* As = buf;
        char* B1s = buf + 16384;
        char* B3s = buf + 24576;
#pragma unroll
        for (int p = 0; p < 4; ++p)
            gload16((const char*)A + ((size_t)(brow + arow[p]) * K + kb) * 2 + ascb[p],
                    As + (wid * 4 + p) * 1024);
#pragma unroll
        for (int p = 0; p < 2; ++p) {
            gload16((const char*)Bt1 + ((size_t)(bcol + brow_[p]) * K + kb) * 2 + bscb[p],
                    B1s + (wid * 2 + p) * 1024);
            gload16((const char*)Bt3 + ((size_t)(bcol + brow_[p]) * K + kb) * 2 + bscb[p],
                    B3s + (wid * 2 + p) * 1024);
        }
    };

    f32x4 acc1[4][2] = {}, acc3[4][2] = {};
    stage(smem[0], 0);
    for (int kt = 0; kt < nK; ++kt) {
        if (kt + 1 < nK) {
            stage(smem[(kt + 1) & 1], (kt + 1) * BKK);
            wait_vm8();
        } else {
            wait_vm0();
        }
        __builtin_amdgcn_s_barrier();
        __builtin_amdgcn_sched_barrier(0);
        const char* As = smem[kt & 1];
        const char* B1s = As + 16384;
        const char* B3s = As + 24576;
#pragma unroll
        for (int kc = 0; kc < 2; ++kc) {
            fp16x8 af[4], b1f[2], b3f[2];
            int boff = kc * 64 + hi * 16;
#pragma unroll
            for (int m = 0; m < 4; ++m) {
                int row = wr + m * 16 + lo;
                af[m] = *(const fp16x8*)(As + row * 128 + (boff ^ ((row & 7) << 4)));
            }
#pragma unroll
            for (int n = 0; n < 2; ++n) {
                int row = wc + n * 16 + lo;
                int o = row * 128 + (boff ^ ((row & 7) << 4));
                b1f[n] = *(const fp16x8*)(B1s + o);
                b3f[n] = *(const fp16x8*)(B3s + o);
            }
#pragma unroll
            for (int m = 0; m < 4; ++m)
#pragma unroll
                for (int n = 0; n < 2; ++n) {
                    acc1[m][n] = __builtin_amdgcn_mfma_f32_16x16x32_f16(af[m], b1f[n], acc1[m][n], 0, 0, 0);
                    acc3[m][n] = __builtin_amdgcn_mfma_f32_16x16x32_f16(af[m], b3f[n], acc3[m][n], 0, 0, 0);
                }
        }
        __builtin_amdgcn_s_barrier();
    }

#pragma unroll
    for (int m = 0; m < 4; ++m) {
        int grow0 = brow + wr + m * 16 + hi * 4;
#pragma unroll
        for (int n = 0; n < 2; ++n) {
            int gcol = bcol + wc + n * 16 + lo;
#pragma unroll
            for (int r = 0; r < 4; ++r) {
                float u = acc1[m][n][r];
                float val = (u / (1.0f + __expf(-u))) * acc3[m][n][r];
                G[(size_t)(grow0 + r) * N + gcol] = (fp16_t)val;
            }
        }
    }
}

// ---------------- Flash attention: sliding-window + global, GQA 4:1 ----------------
__global__ __launch_bounds__(256, 2) void attn_kernel(const fp16_t* __restrict__ qkv,
                                                      const fp16_t* __restrict__ vT,
                                                      fp16_t* __restrict__ o) {
    __shared__ __align__(16) char smem[16384 + 16384 + 4 * 2304];
    char* Ks = smem;
    char* VTs = smem + 16384;
    char* Ps = smem + 32768;

    int t = blockIdx.x, qh = blockIdx.y;
    int kvh = qh >> 2;
    int qs = t * 64;
    int tid = threadIdx.x, lane = tid & 63, wid = tid >> 6;
    int lo = lane & 15, hi = lane >> 4;

    fp16x8 qf[4];
    {
        const fp16_t* qptr = qkv + (size_t)(qs + wid * 16 + lo) * 3072 + qh * 128 + hi * 8;
#pragma unroll
        for (int kc = 0; kc < 4; ++kc) qf[kc] = *(const fp16x8*)(qptr + kc * 32);
    }

    f32x4 oacc[8] = {};
    float m_r[4], l_r[4];
#pragma unroll
    for (int r = 0; r < 4; ++r) { m_r[r] = -1e30f; l_r[r] = 0.0f; }

    int lot = qs - (WIN - 1);
    int jt_lo = lot <= 0 ? 0 : (lot >> 6);
    int nt = (jt_lo > 0) ? (t - jt_lo + 2) : (t + 1);

    for (int ti = 0; ti < nt; ++ti) {
        int jt = (jt_lo > 0) ? (ti == 0 ? 0 : jt_lo + ti - 1) : ti;
        int js = jt * 64;
        __syncthreads();
#pragma unroll
        for (int p = 0; p < 4; ++p) {
            int ci = wid * 4 + p;
            int idx = ci * 64 + lane;
            int krow = idx >> 4;
            int kcb = (idx & 15) << 4;
            int kscb = kcb ^ ((krow & 7) << 4);
            gload16((const char*)qkv + ((size_t)(js + krow) * 3072 + 2048 + kvh * 128) * 2 + kscb,
                    Ks + ci * 1024);
            int vrow = idx >> 3;
            int vcb = (idx & 7) << 4;
            int vscb = vcb ^ ((vrow & 7) << 4);
            gload16((const char*)vT + ((size_t)(kvh * 128 + vrow) * 2048 + js) * 2 + vscb,
                    VTs + ci * 1024);
        }
        __syncthreads();

        f32x4 s[4] = {};
#pragma unroll
        for (int kc = 0; kc < 4; ++kc) {
#pragma unroll
            for (int jc = 0; jc < 4; ++jc) {
                int row = jc * 16 + lo;
                fp16x8 kf = *(const fp16x8*)(Ks + row * 256 + ((kc * 64 + hi * 16) ^ ((row & 7) << 4)));
                s[jc] = __builtin_amdgcn_mfma_f32_16x16x32_f16(qf[kc], kf, s[jc], 0, 0, 0);
            }
        }

        float mt[4] = { -1e30f, -1e30f, -1e30f, -1e30f };
#pragma unroll
        for (int jc = 0; jc < 4; ++jc) {
            int j = js + jc * 16 + lo;
#pragma unroll
            for (int r = 0; r < 4; ++r) {
                int i = qs + wid * 16 + hi * 4 + r;
                bool ok = (j <= i) && (((i - j) < WIN) || (j < NG) || (i < NG));
                float sv = ok ? s[jc][r] : -1e30f;
                s[jc][r] = sv;
                mt[r] = fmaxf(mt[r], sv);
            }
        }
#pragma unroll
        for (int m2 = 1; m2 <= 8; m2 <<= 1)
#pragma unroll
            for (int r = 0; r < 4; ++r) mt[r] = fmaxf(mt[r], __shfl_xor(mt[r], m2));
        float sf[4], psum[4];
#pragma unroll
        for (int r = 0; r < 4; ++r) {
            float mn = fmaxf(m_r[r], mt[r]);
            sf[r] = __expf(m_r[r] - mn);
            m_r[r] = mn;
            psum[r] = 0.0f;
        }
#pragma unroll
        for (int jc = 0; jc < 4; ++jc)
#pragma unroll
            for (int r = 0; r < 4; ++r) {
                float p = __expf(s[jc][r] - m_r[r]);
                s[jc][r] = p;
                psum[r] += p;
            }
#pragma unroll
        for (int m2 = 1; m2 <= 8; m2 <<= 1)
#pragma unroll
            for (int r = 0; r < 4; ++r) psum[r] += __shfl_xor(psum[r], m2);
#pragma unroll
        for (int r = 0; r < 4; ++r) l_r[r] = l_r[r] * sf[r] + psum[r];
#pragma unroll
        for (int nc = 0; nc < 8; ++nc)
#pragma unroll
            for (int r = 0; r < 4; ++r) oacc[nc][r] *= sf[r];

        char* Pb = Ps + wid * 2304;
#pragma unroll
        for (int jc = 0; jc < 4; ++jc)
#pragma unroll
            for (int r = 0; r < 4; ++r)
                *(fp16_t*)(Pb + (hi * 4 + r) * 144 + (jc * 16 + lo) * 2) = (fp16_t)s[jc][r];
        fp16x8 pa[2];
#pragma unroll
        for (int jc2 = 0; jc2 < 2; ++jc2)
            pa[jc2] = *(const fp16x8*)(Pb + lo * 144 + jc2 * 64 + hi * 16);

#pragma unroll
        for (int jc2 = 0; jc2 < 2; ++jc2)
#pragma unroll
            for (int nc = 0; nc < 8; ++nc) {
                int row = nc * 16 + lo;
                fp16x8 vf = *(const fp16x8*)(VTs + row * 128 + ((jc2 * 64 + hi * 16) ^ ((row & 7) << 4)));
                oacc[nc] = __builtin_amdgcn_mfma_f32_16x16x32_f16(pa[jc2], vf, oacc[nc], 0, 0, 0);
            }
    }

#pragma unroll
    for (int r = 0; r < 4; ++r) {
        float inv = 1.0f / l_r[r];
        int orow = qs + wid * 16 + hi * 4 + r;
#pragma unroll
        for (int nc = 0; nc < 8; ++nc)
            o[(size_t)orow * 2048 + qh * 128 + nc * 16 + lo] = (fp16_t)(oacc[nc][r] * inv);
    }
}

// ---------------- host ----------------
extern "C" void kernel_launch(void* const* d_in, const int* in_sizes, int n_in,
                              void* d_out, int out_size, void* d_ws, size_t ws_size,
                              hipStream_t stream) {
    // setup_inputs() dict order: x, g_attn, g_ffn, wq, wk, wv, wo, w1, w3, w2
    const float* x = (const float*)d_in[0];
    const float* g_attn = (const float*)d_in[1];
    const float* g_ffn = (const float*)d_in[2];
    const float* wq = (const float*)d_in[3];
    const float* wk = (const float*)d_in[4];
    const float* wv = (const float*)d_in[5];
    const float* wo = (const float*)d_in[6];
    const float* w1 = (const float*)d_in[7];  // gate proj (D,F)
    const float* w3 = (const float*)d_in[8];  // up proj   (D,F)  <- dict order!
    const float* w2 = (const float*)d_in[9];  // down proj (F,D)  <- dict order!
    float* out = (float*)d_out;               // doubles as x1 buffer

    char* ws = (char*)d_ws;
    size_t off = 0;
    auto alloc = [&](size_t bytes) {
        char* p = ws + off;
        off += (bytes + 255) & ~(size_t)255;
        return p;
    };
    // hbuf+wqkvT+vTb contiguous (8.39+12.58+2.10 = 23.07MB), all dead by FFN time
    // -> overlaid by w3T (5632*2048*2 = 23.07MB exactly).
    fp16_t* hbuf  = (fp16_t*)alloc(2048ull * 2048 * 2);  // h, then attn out o
    fp16_t* wqkvT = (fp16_t*)alloc(3072ull * 2048 * 2);  // qkv weights, then woT
    fp16_t* vTb   = (fp16_t*)alloc(512ull * 2048 * 2);
    fp16_t* qkv   = (fp16_t*)alloc(2048ull * 3072 * 2);  // q|k (v direct to vTb), then h2
    fp16_t* gbuf  = (fp16_t*)alloc(2048ull * 5632 * 2);  // g = silu(u1)*u3
    fp16_t* wbigT = (fp16_t*)alloc(5632ull * 2048 * 2);  // w1T, then w2T
    if (off > ws_size) {  // diagnostic fallback: absmax ~= max|ref|
        hipMemsetAsync(d_out, 0, (size_t)out_size * 4, stream);
        return;
    }
    fp16_t* w3T = hbuf;  // overlay (valid only after wo GEMM)

    // QKV weights -> [N][K] fp16 concat (single merged dispatch)
    transpose_qkv3<<<dim3(48, 32), 256, 0, stream>>>(wq, wk, wv, wqkvT);
    // h = RMSNorm(x) * g_attn
    rmsnorm_kernel<<<2048, 256, 0, stream>>>(x, g_attn, hbuf);
    // qkv = h @ [wq|wk|wv]; fused QK-norm; v heads written transposed -> vTb
    gemm_qkv<<<dim3(24, 16), 256, 0, stream>>>(hbuf, wqkvT, qkv, vTb, 2048, 3072, 2048);
    // attention -> o (reuses hbuf; h no longer needed)
    attn_kernel<<<dim3(32, 16), 256, 0, stream>>>(qkv, vTb, hbuf);
    // x1 = x + o @ wo  (BN=64, 512 blocks, fused residual, fp32 -> d_out)
    transpose_one<<<dim3(32, 32), 256, 0, stream>>>(wo, wqkvT, 2048, 2048);
    gemm_bt64_resid<<<dim3(32, 16), 256, 0, stream>>>(hbuf, wqkvT, out, x, 2048, 2048, 2048);
    // h2 = RMSNorm(x1) * g_ffn  (-> qkv buffer)
    rmsnorm_kernel<<<2048, 256, 0, stream>>>(out, g_ffn, qkv);
    // w1,w3 transposed in one dispatch (w3T overlays dead hbuf/wqkvT/vTb)
    transpose_w13<<<dim3(88, 32, 2), 256, 0, stream>>>(w1, w3, wbigT, w3T);
    // g = silu(h2@w1) * (h2@w3), half-width dual-acc fusion (1408 blocks)
    gemm_u1u3_half<<<dim3(88, 16), 256, 0, stream>>>(qkv, wbigT, w3T, gbuf, 2048, 5632, 2048);
    // out = x1 + g @ w2  (BN=64, 512 blocks, fused residual, in-place on d_out)
    transpose_one<<<dim3(32, 88), 256, 0, stream>>>(w2, wbigT, 5632, 2048);
    gemm_bt64_resid<<<dim3(32, 16), 256, 0, stream>>>(gbuf, wbigT, out, out, 2048, 2048, 5632);
}